// Round 1
// baseline (3396.263 us; speedup 1.0000x reference)
//
#include <hip/hip_runtime.h>

#define UN 100000
#define INN 50000
#define UIN 150000
#define DN 64
#define KK 192

// mish(x) = x * tanh(softplus(x)) = x * (t^2 + 2t) / (t^2 + 2t + 2), t = e^x
__device__ __forceinline__ float mish_f(float x) {
  float t = __expf(x);
  float num = fmaf(t, t, 2.0f * t);
  float m = x * num / (num + 2.0f);
  return (x > 20.0f) ? x : m;
}

__global__ void init_kernel(const float* __restrict__ ue, const float* __restrict__ ie,
                            float* __restrict__ ego, float* __restrict__ acc) {
  size_t i = (size_t)blockIdx.x * blockDim.x + threadIdx.x;
  size_t total = (size_t)UIN * DN;
  if (i >= total) return;
  size_t usz = (size_t)UN * DN;
  float v = (i < usz) ? ue[i] : ie[i - usz];
  ego[i] = v;
  acc[i] = v;
}

__global__ void transpose_w(const float* __restrict__ W, float* __restrict__ Wt, int M, int K) {
  int i = blockIdx.x * blockDim.x + threadIdx.x;
  if (i >= M * K) return;
  int m = i / K, k = i % K;
  Wt[k * M + m] = W[m * K + k];
}

// one wave per nnz; lane = feature dim
__global__ void spmm_atomic(const int* __restrict__ rows, const int* __restrict__ cols,
                            const float* __restrict__ vals, const float* __restrict__ x,
                            float* __restrict__ out, int nnz) {
  long long idx = (long long)blockIdx.x * blockDim.x + threadIdx.x;
  int e = (int)(idx >> 6);
  if (e >= nnz) return;
  int d = (int)(idx & 63);
  int r = rows[e];
  int c = cols[e];
  float v = vals[e];
  atomicAdd(out + (((size_t)r) << 6) + d, v * x[(((size_t)c) << 6) + d]);
}

// Fused 3-GEMM MLP per 64-row tile. blockDim = 192.
__global__ __launch_bounds__(192) void fusion_kernel(
    const float* __restrict__ aout,  // spmm(A) result, rows [0,UIN); ue = aout[:UN]
    const float* __restrict__ sout,  // spmm(S) result, rows [0,UN)
    const float* __restrict__ Wt1, const float* __restrict__ b1,
    const float* __restrict__ Wt2, const float* __restrict__ b2,
    const float* __restrict__ Wt3, const float* __restrict__ b3,
    float* __restrict__ t3out, float* __restrict__ sumsq) {
  __shared__ __align__(16) float As[KK][68];  // k-major, padded (52.2 KB)
  __shared__ float ssred[3];
  const int tid = threadIdx.x;
  const int g = tid >> 6;   // wave id 0..2
  const int d = tid & 63;   // lane
  const int r0 = blockIdx.x * 64;

  // stage cat = [ue, social, ue*social], k-major
  for (int r = g; r < 64; r += 3) {
    int row = r0 + r;
    float u = 0.0f, s = 0.0f;
    if (row < UN) {
      u = aout[(((size_t)row) << 6) + d];
      s = sout[(((size_t)row) << 6) + d];
    }
    As[d][r] = u;
    As[64 + d][r] = s;
    As[128 + d][r] = u * s;
  }
  __syncthreads();

  const int j = tid;  // output column 0..191
  float4 acc[16];

  // ---- GEMM1: t1 = mish(cat @ W1^T + b1) ----
  #pragma unroll
  for (int q = 0; q < 16; ++q) acc[q] = make_float4(0.f, 0.f, 0.f, 0.f);
  for (int k = 0; k < KK; ++k) {
    float w = Wt1[k * KK + j];
    const float4* ar = (const float4*)(&As[k][0]);
    #pragma unroll
    for (int q = 0; q < 16; ++q) {
      float4 a = ar[q];
      acc[q].x = fmaf(a.x, w, acc[q].x);
      acc[q].y = fmaf(a.y, w, acc[q].y);
      acc[q].z = fmaf(a.z, w, acc[q].z);
      acc[q].w = fmaf(a.w, w, acc[q].w);
    }
  }
  {
    float bb = b1[j];
    __syncthreads();  // all reads of cat done
    #pragma unroll
    for (int q = 0; q < 16; ++q) {
      float4 v;
      v.x = mish_f(acc[q].x + bb);
      v.y = mish_f(acc[q].y + bb);
      v.z = mish_f(acc[q].z + bb);
      v.w = mish_f(acc[q].w + bb);
      *(float4*)(&As[j][q * 4]) = v;
    }
  }
  __syncthreads();

  // ---- GEMM2: t2 = mish(t1 @ W2^T + b2) ----
  #pragma unroll
  for (int q = 0; q < 16; ++q) acc[q] = make_float4(0.f, 0.f, 0.f, 0.f);
  for (int k = 0; k < KK; ++k) {
    float w = Wt2[k * KK + j];
    const float4* ar = (const float4*)(&As[k][0]);
    #pragma unroll
    for (int q = 0; q < 16; ++q) {
      float4 a = ar[q];
      acc[q].x = fmaf(a.x, w, acc[q].x);
      acc[q].y = fmaf(a.y, w, acc[q].y);
      acc[q].z = fmaf(a.z, w, acc[q].z);
      acc[q].w = fmaf(a.w, w, acc[q].w);
    }
  }
  {
    float bb = b2[j];
    __syncthreads();
    #pragma unroll
    for (int q = 0; q < 16; ++q) {
      float4 v;
      v.x = mish_f(acc[q].x + bb);
      v.y = mish_f(acc[q].y + bb);
      v.z = mish_f(acc[q].z + bb);
      v.w = mish_f(acc[q].w + bb);
      *(float4*)(&As[j][q * 4]) = v;
    }
  }
  __syncthreads();

  // ---- GEMM3: t3 = t2 @ W3^T + b3, cols = 64, rows split over 3 waves ----
  // wave g covers rows [g*20, g*20+24) (quads g*5 .. g*5+5); overlap rows
  // computed twice (identical), counted once in sumsq.
  float4 acc3[6];
  #pragma unroll
  for (int q = 0; q < 6; ++q) acc3[q] = make_float4(0.f, 0.f, 0.f, 0.f);
  const int qbase = g * 5;
  for (int k = 0; k < KK; ++k) {
    float w = Wt3[k * DN + d];
    const float4* ar = (const float4*)(&As[k][0]);
    #pragma unroll
    for (int q = 0; q < 6; ++q) {
      float4 a = ar[qbase + q];
      acc3[q].x = fmaf(a.x, w, acc3[q].x);
      acc3[q].y = fmaf(a.y, w, acc3[q].y);
      acc3[q].z = fmaf(a.z, w, acc3[q].z);
      acc3[q].w = fmaf(a.w, w, acc3[q].w);
    }
  }
  float b3v = b3[d];
  float lss = 0.0f;
  #pragma unroll
  for (int q = 0; q < 6; ++q) {
    int rbase = r0 + g * 20 + q * 4;
    float4 v;
    v.x = acc3[q].x + b3v;
    v.y = acc3[q].y + b3v;
    v.z = acc3[q].z + b3v;
    v.w = acc3[q].w + b3v;
    bool count = (g == 0) || (q >= 1);
    if (rbase + 0 < UN) { t3out[(((size_t)(rbase + 0)) << 6) + d] = v.x; if (count) lss = fmaf(v.x, v.x, lss); }
    if (rbase + 1 < UN) { t3out[(((size_t)(rbase + 1)) << 6) + d] = v.y; if (count) lss = fmaf(v.y, v.y, lss); }
    if (rbase + 2 < UN) { t3out[(((size_t)(rbase + 2)) << 6) + d] = v.z; if (count) lss = fmaf(v.z, v.z, lss); }
    if (rbase + 3 < UN) { t3out[(((size_t)(rbase + 3)) << 6) + d] = v.w; if (count) lss = fmaf(v.w, v.w, lss); }
  }
  #pragma unroll
  for (int off = 32; off > 0; off >>= 1) lss += __shfl_down(lss, off);
  if (d == 0) ssred[g] = lss;
  __syncthreads();
  if (tid == 0) atomicAdd(sumsq, ssred[0] + ssred[1] + ssred[2]);
}

__global__ void finalize_kernel(const float* __restrict__ t3, const float* __restrict__ sumsq,
                                const float* __restrict__ aout, float* __restrict__ ego,
                                float* __restrict__ acc) {
  size_t i = (size_t)blockIdx.x * blockDim.x + threadIdx.x;
  size_t total = (size_t)UIN * DN;
  if (i >= total) return;
  size_t usz = (size_t)UN * DN;
  float v;
  if (i < usz) {
    float inv = 1.0f / sqrtf(sumsq[0]);
    v = t3[i] * inv;
  } else {
    v = aout[i];
  }
  ego[i] = v;
  acc[i] += v;
}

__global__ void scale_out(const float* __restrict__ acc, float* __restrict__ out) {
  size_t i = (size_t)blockIdx.x * blockDim.x + threadIdx.x;
  size_t total = (size_t)UIN * DN;
  if (i >= total) return;
  out[i] = acc[i] * 0.25f;
}

extern "C" void kernel_launch(void* const* d_in, const int* in_sizes, int n_in,
                              void* d_out, int out_size, void* d_ws, size_t ws_size,
                              hipStream_t stream) {
  const float* user_emb = (const float*)d_in[0];
  const float* item_emb = (const float*)d_in[1];
  const int* A_rows = (const int*)d_in[2];
  const int* A_cols = (const int*)d_in[3];
  const float* A_vals = (const float*)d_in[4];
  const int* S_rows = (const int*)d_in[5];
  const int* S_cols = (const int*)d_in[6];
  const float* S_vals = (const float*)d_in[7];
  const float* W1 = (const float*)d_in[8];
  const float* b1 = (const float*)d_in[9];
  const float* W2 = (const float*)d_in[10];
  const float* b2 = (const float*)d_in[11];
  const float* W3 = (const float*)d_in[12];
  const float* b3 = (const float*)d_in[13];
  const int nnzA = in_sizes[2];
  const int nnzS = in_sizes[5];

  float* ws = (float*)d_ws;
  size_t off = 0;
  float* ego = ws + off;  off += (size_t)UIN * DN;
  float* acc = ws + off;  off += (size_t)UIN * DN;
  float* aout = ws + off; off += (size_t)UIN * DN;   // zeroed each layer
  float* sout = ws + off; off += (size_t)UN * DN;    // zeroed each layer; aliased as t3
  float* ss = ws + off;   off += 16;                 // zeroed each layer
  float* Wt1 = ws + off;  off += 192 * 192;
  float* Wt2 = ws + off;  off += 192 * 192;
  float* Wt3 = ws + off;  off += 192 * 64;
  float* t3 = sout;  // safe alias: each block reads sout rows before writing t3 rows

  const size_t total = (size_t)UIN * DN;
  const int nblk_elem = (int)((total + 255) / 256);

  init_kernel<<<nblk_elem, 256, 0, stream>>>(user_emb, item_emb, ego, acc);
  transpose_w<<<(192 * 192 + 255) / 256, 256, 0, stream>>>(W1, Wt1, 192, 192);
  transpose_w<<<(192 * 192 + 255) / 256, 256, 0, stream>>>(W2, Wt2, 192, 192);
  transpose_w<<<(192 * 64 + 255) / 256, 256, 0, stream>>>(W3, Wt3, 64, 192);

  const size_t zbytes = ((size_t)UIN * DN + (size_t)UN * DN + 16) * sizeof(float);

  for (int layer = 0; layer < 3; ++layer) {
    hipMemsetAsync(aout, 0, zbytes, stream);  // zeros aout, sout(t3), ss

    long long tA = (long long)nnzA * 64;
    spmm_atomic<<<(int)((tA + 255) / 256), 256, 0, stream>>>(A_rows, A_cols, A_vals, ego, aout, nnzA);
    long long tS = (long long)nnzS * 64;
    spmm_atomic<<<(int)((tS + 255) / 256), 256, 0, stream>>>(S_rows, S_cols, S_vals, ego, sout, nnzS);

    fusion_kernel<<<(UN + 63) / 64, 192, 0, stream>>>(aout, sout, Wt1, b1, Wt2, b2, Wt3, b3, t3, ss);

    finalize_kernel<<<nblk_elem, 256, 0, stream>>>(t3, ss, aout, ego, acc);
  }

  scale_out<<<nblk_elem, 256, 0, stream>>>(acc, (float*)d_out);
}

// Round 5
// 3055.101 us; speedup vs baseline: 1.1117x; 1.1117x over previous
//
#include <hip/hip_runtime.h>

#define UN 100000
#define INN 50000
#define UIN 150000
#define DN 64
#define KK 192
#define PAD 68  // 68*4=272B row stride: 16B-aligned for float4 LDS ops; 52.2KB -> 3 blocks/CU

// mish(x) = x * tanh(softplus(x)) = x * (t^2 + 2t) / (t^2 + 2t + 2), t = e^x
__device__ __forceinline__ float mish_f(float x) {
  float t = __expf(x);
  float num = fmaf(t, t, 2.0f * t);
  float m = x * num / (num + 2.0f);
  return (x > 20.0f) ? x : m;
}

__global__ void init_kernel(const float* __restrict__ ue, const float* __restrict__ ie,
                            float* __restrict__ ego, float* __restrict__ outacc) {
  size_t i = (size_t)blockIdx.x * blockDim.x + threadIdx.x;
  size_t total = (size_t)UIN * DN;
  if (i >= total) return;
  size_t usz = (size_t)UN * DN;
  float v = (i < usz) ? ue[i] : ie[i - usz];
  ego[i] = v;
  outacc[i] = v;
}

__global__ void transpose_w(const float* __restrict__ W, float* __restrict__ Wt, int M, int K) {
  int i = blockIdx.x * blockDim.x + threadIdx.x;
  if (i >= M * K) return;
  int m = i / K, k = i % K;
  Wt[k * M + m] = W[m * K + k];
}

// ---------------- CSR build ----------------
__global__ void hist_kernel(const int* __restrict__ rows, int* __restrict__ cnt, int nnz) {
  int e = blockIdx.x * blockDim.x + threadIdx.x;
  if (e < nnz) atomicAdd(&cnt[rows[e]], 1);
}

__global__ __launch_bounds__(1024) void scan_kernel(const int* __restrict__ cnt,
                                                    int* __restrict__ rowptr,
                                                    int* __restrict__ tmp, int n) {
  __shared__ int part[1024];
  int tid = threadIdx.x;
  int per = (n + 1023) >> 10;
  int start = tid * per;
  int end = min(start + per, n);
  int s = 0;
  for (int i = start; i < end; ++i) s += cnt[i];
  part[tid] = s;
  __syncthreads();
  for (int off = 1; off < 1024; off <<= 1) {
    int v = (tid >= off) ? part[tid - off] : 0;
    __syncthreads();
    part[tid] += v;
    __syncthreads();
  }
  int run = (tid == 0) ? 0 : part[tid - 1];
  for (int i = start; i < end; ++i) {
    rowptr[i] = run;
    tmp[i] = run;
    run += cnt[i];
  }
  if (start < n && end == n) rowptr[n] = run;
}

__global__ void scatter_kernel(const int* __restrict__ rows, const int* __restrict__ cols,
                               const float* __restrict__ vals, int* __restrict__ tmp,
                               int2* __restrict__ packed, int nnz) {
  int e = blockIdx.x * blockDim.x + threadIdx.x;
  if (e >= nnz) return;
  int pos = atomicAdd(&tmp[rows[e]], 1);
  packed[pos] = make_int2(cols[e], __float_as_int(vals[e]));
}

// ---------------- SpMM (CSR, gather, no atomics) ----------------
// one wave per row; lane = feature dim; 2-deep unroll for 2 outstanding gathers
__global__ __launch_bounds__(256) void spmm_csr(const int* __restrict__ rowptr,
                                                const int2* __restrict__ packed,
                                                const float* __restrict__ x,
                                                float* __restrict__ out, int nrows) {
  int r = blockIdx.x * 4 + (threadIdx.x >> 6);
  if (r >= nrows) return;
  int d = threadIdx.x & 63;
  int beg = rowptr[r], end = rowptr[r + 1];
  float a0 = 0.f, a1 = 0.f;
  int e = beg;
  for (; e + 2 <= end; e += 2) {
    int2 p0 = packed[e];
    int2 p1 = packed[e + 1];
    float x0 = x[((size_t)p0.x << 6) + d];
    float x1 = x[((size_t)p1.x << 6) + d];
    a0 = fmaf(__int_as_float(p0.y), x0, a0);
    a1 = fmaf(__int_as_float(p1.y), x1, a1);
  }
  if (e < end) {
    int2 p = packed[e];
    a0 = fmaf(__int_as_float(p.y), x[((size_t)p.x << 6) + d], a0);
  }
  out[((size_t)r << 6) + d] = a0 + a1;
}

// ---------------- Fused 3-GEMM MLP, 384 threads, 64-row tile ----------------
__global__ __launch_bounds__(384) void fusion_kernel(
    const float* __restrict__ aout, const float* __restrict__ sout,
    const float* __restrict__ Wt1, const float* __restrict__ b1,
    const float* __restrict__ Wt2, const float* __restrict__ b2,
    const float* __restrict__ Wt3, const float* __restrict__ b3,
    float* __restrict__ t3out, float* __restrict__ sumsq) {
  __shared__ __align__(16) float As[KK][PAD];  // k-major, 52.2 KB -> 3 blocks/CU
  __shared__ float ssred[6];
  const int tid = threadIdx.x;
  const int g = tid >> 6;     // wave 0..5
  const int d = tid & 63;     // lane
  const int jj = tid % KK;    // output column 0..191
  const int rr = tid / KK;    // row half 0..1 (uniform within a wave)
  const int r0 = blockIdx.x * 64;

  // stage cat = [ue, social, ue*social], k-major
  for (int r = g; r < 64; r += 6) {
    int row = r0 + r;
    float u = 0.f, s = 0.f;
    if (row < UN) {
      u = aout[((size_t)row << 6) + d];
      s = sout[((size_t)row << 6) + d];
    }
    As[d][r] = u;
    As[64 + d][r] = s;
    As[128 + d][r] = u * s;
  }
  __syncthreads();

  float4 acc[8];

  // ---- GEMM1: t1 = mish(cat @ W1^T + b1); thread = col jj, rows rr*32..rr*32+31 ----
  #pragma unroll
  for (int q = 0; q < 8; ++q) acc[q] = make_float4(0.f, 0.f, 0.f, 0.f);
  for (int k0 = 0; k0 < KK; k0 += 8) {
    float w[8];
    #pragma unroll
    for (int kk = 0; kk < 8; ++kk) w[kk] = Wt1[(k0 + kk) * KK + jj];
    #pragma unroll
    for (int kk = 0; kk < 8; ++kk) {
      const float4* ar = (const float4*)(&As[k0 + kk][rr * 32]);
      #pragma unroll
      for (int q = 0; q < 8; ++q) {
        float4 a = ar[q];
        acc[q].x = fmaf(a.x, w[kk], acc[q].x);
        acc[q].y = fmaf(a.y, w[kk], acc[q].y);
        acc[q].z = fmaf(a.z, w[kk], acc[q].z);
        acc[q].w = fmaf(a.w, w[kk], acc[q].w);
      }
    }
  }
  {
    float bb = b1[jj];
    __syncthreads();  // all reads of cat done
    #pragma unroll
    for (int q = 0; q < 8; ++q) {
      float4 v;
      v.x = mish_f(acc[q].x + bb);
      v.y = mish_f(acc[q].y + bb);
      v.z = mish_f(acc[q].z + bb);
      v.w = mish_f(acc[q].w + bb);
      *(float4*)(&As[jj][rr * 32 + q * 4]) = v;
    }
  }
  __syncthreads();

  // ---- GEMM2: t2 = mish(t1 @ W2^T + b2) ----
  #pragma unroll
  for (int q = 0; q < 8; ++q) acc[q] = make_float4(0.f, 0.f, 0.f, 0.f);
  for (int k0 = 0; k0 < KK; k0 += 8) {
    float w[8];
    #pragma unroll
    for (int kk = 0; kk < 8; ++kk) w[kk] = Wt2[(k0 + kk) * KK + jj];
    #pragma unroll
    for (int kk = 0; kk < 8; ++kk) {
      const float4* ar = (const float4*)(&As[k0 + kk][rr * 32]);
      #pragma unroll
      for (int q = 0; q < 8; ++q) {
        float4 a = ar[q];
        acc[q].x = fmaf(a.x, w[kk], acc[q].x);
        acc[q].y = fmaf(a.y, w[kk], acc[q].y);
        acc[q].z = fmaf(a.z, w[kk], acc[q].z);
        acc[q].w = fmaf(a.w, w[kk], acc[q].w);
      }
    }
  }
  {
    float bb = b2[jj];
    __syncthreads();
    #pragma unroll
    for (int q = 0; q < 8; ++q) {
      float4 v;
      v.x = mish_f(acc[q].x + bb);
      v.y = mish_f(acc[q].y + bb);
      v.z = mish_f(acc[q].z + bb);
      v.w = mish_f(acc[q].w + bb);
      *(float4*)(&As[jj][rr * 32 + q * 4]) = v;
    }
  }
  __syncthreads();

  // ---- GEMM3: t3 = t2 @ W3^T + b3; lane = col d; wave g owns 2-3 row-quads ----
  const int nq = (g < 4) ? 3 : 2;
  const int qb = (g < 4) ? 3 * g : 12 + 2 * (g - 4);
  float4 a3[3];
  #pragma unroll
  for (int q = 0; q < 3; ++q) a3[q] = make_float4(0.f, 0.f, 0.f, 0.f);
  for (int k0 = 0; k0 < KK; k0 += 8) {
    float w[8];
    #pragma unroll
    for (int kk = 0; kk < 8; ++kk) w[kk] = Wt3[(k0 + kk) * DN + d];
    #pragma unroll
    for (int kk = 0; kk < 8; ++kk) {
      const float4* ar = (const float4*)(&As[k0 + kk][qb * 4]);
      #pragma unroll
      for (int q = 0; q < 3; ++q) {
        if (q < nq) {
          float4 a = ar[q];
          a3[q].x = fmaf(a.x, w[kk], a3[q].x);
          a3[q].y = fmaf(a.y, w[kk], a3[q].y);
          a3[q].z = fmaf(a.z, w[kk], a3[q].z);
          a3[q].w = fmaf(a.w, w[kk], a3[q].w);
        }
      }
    }
  }
  float b3v = b3[d];
  float lss = 0.f;
  #pragma unroll
  for (int q = 0; q < 3; ++q) {
    if (q < nq) {
      int rbase = r0 + (qb + q) * 4;
      float4 v;
      v.x = a3[q].x + b3v;
      v.y = a3[q].y + b3v;
      v.z = a3[q].z + b3v;
      v.w = a3[q].w + b3v;
      if (rbase + 0 < UN) { t3out[((size_t)(rbase + 0) << 6) + d] = v.x; lss = fmaf(v.x, v.x, lss); }
      if (rbase + 1 < UN) { t3out[((size_t)(rbase + 1) << 6) + d] = v.y; lss = fmaf(v.y, v.y, lss); }
      if (rbase + 2 < UN) { t3out[((size_t)(rbase + 2) << 6) + d] = v.z; lss = fmaf(v.z, v.z, lss); }
      if (rbase + 3 < UN) { t3out[((size_t)(rbase + 3) << 6) + d] = v.w; lss = fmaf(v.w, v.w, lss); }
    }
  }
  #pragma unroll
  for (int off = 32; off > 0; off >>= 1) lss += __shfl_down(lss, off);
  if (d == 0) ssred[g] = lss;
  __syncthreads();
  if (tid == 0) {
    float s = 0.f;
    #pragma unroll
    for (int i = 0; i < 6; ++i) s += ssred[i];
    atomicAdd(sumsq, s);
  }
}

__global__ void finalize_kernel(const float* __restrict__ t3, const float* __restrict__ sumsq,
                                const float* __restrict__ aout, float* __restrict__ ego,
                                float* __restrict__ outacc, int last) {
  size_t i = (size_t)blockIdx.x * blockDim.x + threadIdx.x;
  size_t total = (size_t)UIN * DN;
  if (i >= total) return;
  size_t usz = (size_t)UN * DN;
  float v;
  if (i < usz) {
    float inv = 1.0f / sqrtf(sumsq[0]);
    v = t3[i] * inv;
  } else {
    v = aout[i];
  }
  if (last) {
    outacc[i] = (outacc[i] + v) * 0.25f;
  } else {
    ego[i] = v;
    outacc[i] += v;
  }
}

extern "C" void kernel_launch(void* const* d_in, const int* in_sizes, int n_in,
                              void* d_out, int out_size, void* d_ws, size_t ws_size,
                              hipStream_t stream) {
  const float* user_emb = (const float*)d_in[0];
  const float* item_emb = (const float*)d_in[1];
  const int* A_rows = (const int*)d_in[2];
  const int* A_cols = (const int*)d_in[3];
  const float* A_vals = (const float*)d_in[4];
  const int* S_rows = (const int*)d_in[5];
  const int* S_cols = (const int*)d_in[6];
  const float* S_vals = (const float*)d_in[7];
  const float* W1 = (const float*)d_in[8];
  const float* b1 = (const float*)d_in[9];
  const float* W2 = (const float*)d_in[10];
  const float* b2 = (const float*)d_in[11];
  const float* W3 = (const float*)d_in[12];
  const float* b3 = (const float*)d_in[13];
  const int nnzA = in_sizes[2];
  const int nnzS = in_sizes[5];

  float* ws = (float*)d_ws;
  size_t off = 0;
  float* ego = ws + off;  off += (size_t)UIN * DN;
  float* aout = ws + off; off += (size_t)UIN * DN;
  float* sout = ws + off; off += (size_t)UN * DN;   // also aliased as t3 (safe: per-block read-then-write)
  float* ss = ws + off;   off += 16;
  float* Wt1 = ws + off;  off += KK * KK;
  float* Wt2 = ws + off;  off += KK * KK;
  float* Wt3 = ws + off;  off += KK * DN;
  int* cntA = (int*)(ws + off);  off += UIN;   // cntA+cntS contiguous for one memset
  int* cntS = (int*)(ws + off);  off += UN;
  int* rptrA = (int*)(ws + off); off += UIN + 1;
  int* tmpA = (int*)(ws + off);  off += UIN;
  int* rptrS = (int*)(ws + off); off += UN + 1;
  int* tmpS = (int*)(ws + off);  off += UN;
  off = (off + 1) & ~(size_t)1;  // 8B align
  int2* pA = (int2*)(ws + off);  off += (size_t)2 * nnzA;
  int2* pS = (int2*)(ws + off);  off += (size_t)2 * nnzS;
  float* outacc = (float*)d_out;
  float* t3 = sout;

  const size_t total = (size_t)UIN * DN;
  const int nblk_elem = (int)((total + 255) / 256);

  // CSR build (every call; graph is static but harness re-poisons ws)
  hipMemsetAsync(cntA, 0, (size_t)(UIN + UN) * sizeof(int), stream);
  hist_kernel<<<(nnzA + 255) / 256, 256, 0, stream>>>(A_rows, cntA, nnzA);
  hist_kernel<<<(nnzS + 255) / 256, 256, 0, stream>>>(S_rows, cntS, nnzS);
  scan_kernel<<<1, 1024, 0, stream>>>(cntA, rptrA, tmpA, UIN);
  scan_kernel<<<1, 1024, 0, stream>>>(cntS, rptrS, tmpS, UN);
  scatter_kernel<<<(nnzA + 255) / 256, 256, 0, stream>>>(A_rows, A_cols, A_vals, tmpA, pA, nnzA);
  scatter_kernel<<<(nnzS + 255) / 256, 256, 0, stream>>>(S_rows, S_cols, S_vals, tmpS, pS, nnzS);

  init_kernel<<<nblk_elem, 256, 0, stream>>>(user_emb, item_emb, ego, outacc);
  transpose_w<<<(KK * KK + 255) / 256, 256, 0, stream>>>(W1, Wt1, KK, KK);
  transpose_w<<<(KK * KK + 255) / 256, 256, 0, stream>>>(W2, Wt2, KK, KK);
  transpose_w<<<(KK * DN + 255) / 256, 256, 0, stream>>>(W3, Wt3, DN, KK);

  for (int layer = 0; layer < 3; ++layer) {
    hipMemsetAsync(ss, 0, 64, stream);
    spmm_csr<<<(UIN + 3) / 4, 256, 0, stream>>>(rptrA, pA, ego, aout, UIN);
    spmm_csr<<<(UN + 3) / 4, 256, 0, stream>>>(rptrS, pS, ego, sout, UN);
    fusion_kernel<<<(UN + 63) / 64, 384, 0, stream>>>(aout, sout, Wt1, b1, Wt2, b2, Wt3, b3, t3, ss);
    finalize_kernel<<<nblk_elem, 256, 0, stream>>>(t3, ss, aout, ego, outacc, layer == 2);
  }
}

// Round 7
// 2603.488 us; speedup vs baseline: 1.3045x; 1.1735x over previous
//
#include <hip/hip_runtime.h>
#include <hip/hip_bf16.h>

#define UN 100000
#define INN 50000
#define UIN 150000
#define DN 64
#define KK 192
#define TILE 32
#define PAD2 36  // 36*4=144B row stride, 16B-aligned; As = 192*36*4 = 27.6KB -> 5 blocks/CU

// mish(x) = x * tanh(softplus(x)) = x * (t^2 + 2t) / (t^2 + 2t + 2), t = e^x
__device__ __forceinline__ float mish_f(float x) {
  float t = __expf(x);
  float num = fmaf(t, t, 2.0f * t);
  float m = x * num / (num + 2.0f);
  return (x > 20.0f) ? x : m;
}

__device__ __forceinline__ float bf2f(ushort u) {
  return __uint_as_float(((unsigned int)u) << 16);
}
__device__ __forceinline__ ushort f2bf(float f) {  // round-to-nearest-even
  unsigned int u = __float_as_uint(f);
  u += 0x7FFFu + ((u >> 16) & 1u);
  return (ushort)(u >> 16);
}

__global__ void init_kernel(const float* __restrict__ ue, const float* __restrict__ ie,
                            ushort* __restrict__ egoh, float* __restrict__ outacc) {
  size_t i = (size_t)blockIdx.x * blockDim.x + threadIdx.x;
  size_t total = (size_t)UIN * DN;
  if (i >= total) return;
  size_t usz = (size_t)UN * DN;
  float v = (i < usz) ? ue[i] : ie[i - usz];
  egoh[i] = f2bf(v);
  outacc[i] = v;
}

__global__ void transpose_w(const float* __restrict__ W, float* __restrict__ Wt, int M, int K) {
  int i = blockIdx.x * blockDim.x + threadIdx.x;
  if (i >= M * K) return;
  int m = i / K, k = i % K;
  Wt[k * M + m] = W[m * K + k];
}

// ---------------- CSR build ----------------
__global__ void hist_kernel(const int* __restrict__ rows, int* __restrict__ cnt, int nnz) {
  int e = blockIdx.x * blockDim.x + threadIdx.x;
  if (e < nnz) atomicAdd(&cnt[rows[e]], 1);
}

__global__ __launch_bounds__(1024) void scan_kernel(const int* __restrict__ cnt,
                                                    int* __restrict__ rowptr,
                                                    int* __restrict__ tmp, int n) {
  __shared__ int part[1024];
  int tid = threadIdx.x;
  int per = (n + 1023) >> 10;
  int start = tid * per;
  int end = min(start + per, n);
  int s = 0;
  for (int i = start; i < end; ++i) s += cnt[i];
  part[tid] = s;
  __syncthreads();
  for (int off = 1; off < 1024; off <<= 1) {
    int v = (tid >= off) ? part[tid - off] : 0;
    __syncthreads();
    part[tid] += v;
    __syncthreads();
  }
  int run = (tid == 0) ? 0 : part[tid - 1];
  for (int i = start; i < end; ++i) {
    rowptr[i] = run;
    tmp[i] = run;
    run += cnt[i];
  }
  if (start < n && end == n) rowptr[n] = run;
}

__global__ void scatter_kernel(const int* __restrict__ rows, const int* __restrict__ cols,
                               const float* __restrict__ vals, int* __restrict__ tmp,
                               int2* __restrict__ packed, int nnz) {
  int e = blockIdx.x * blockDim.x + threadIdx.x;
  if (e >= nnz) return;
  int pos = atomicAdd(&tmp[rows[e]], 1);
  packed[pos] = make_int2(cols[e], __float_as_int(vals[e]));
}

// ---------------- SpMM (CSR gather, bf16 source, unroll-4) ----------------
__global__ __launch_bounds__(256) void spmm_csr(const int* __restrict__ rowptr,
                                                const int2* __restrict__ packed,
                                                const ushort* __restrict__ xh,
                                                float* __restrict__ out, int nrows) {
  int r = blockIdx.x * 4 + (threadIdx.x >> 6);
  if (r >= nrows) return;
  int d = threadIdx.x & 63;
  int beg = rowptr[r], end = rowptr[r + 1];
  float a0 = 0.f, a1 = 0.f, a2 = 0.f, a3 = 0.f;
  int e = beg;
  for (; e + 4 <= end; e += 4) {
    int2 p0 = packed[e];
    int2 p1 = packed[e + 1];
    int2 p2 = packed[e + 2];
    int2 p3 = packed[e + 3];
    float x0 = bf2f(xh[((size_t)p0.x << 6) + d]);
    float x1 = bf2f(xh[((size_t)p1.x << 6) + d]);
    float x2 = bf2f(xh[((size_t)p2.x << 6) + d]);
    float x3 = bf2f(xh[((size_t)p3.x << 6) + d]);
    a0 = fmaf(__int_as_float(p0.y), x0, a0);
    a1 = fmaf(__int_as_float(p1.y), x1, a1);
    a2 = fmaf(__int_as_float(p2.y), x2, a2);
    a3 = fmaf(__int_as_float(p3.y), x3, a3);
  }
  for (; e < end; ++e) {
    int2 p = packed[e];
    a0 = fmaf(__int_as_float(p.y), bf2f(xh[((size_t)p.x << 6) + d]), a0);
  }
  out[((size_t)r << 6) + d] = (a0 + a1) + (a2 + a3);
}

// ---------------- Fused 3-GEMM MLP, 384 threads, 32-row tile ----------------
__global__ __launch_bounds__(384) void fusion_kernel(
    const float* __restrict__ aout, const float* __restrict__ sout,
    const float* __restrict__ Wt1, const float* __restrict__ b1,
    const float* __restrict__ Wt2, const float* __restrict__ b2,
    const float* __restrict__ Wt3, const float* __restrict__ b3,
    float* __restrict__ t3out, float* __restrict__ sumsq) {
  __shared__ __align__(16) float As[KK][PAD2];  // k-major, 27.6 KB -> 5 blocks/CU
  __shared__ float ssred[6];
  const int tid = threadIdx.x;
  const int g = tid >> 6;     // wave 0..5
  const int d = tid & 63;     // lane
  const int jj = tid % KK;    // output column 0..191
  const int rr = tid / KK;    // row half 0..1 (uniform within a wave)
  const int r0 = blockIdx.x * TILE;  // UN = 3125*32 exactly -> no ragged tail

  // stage cat = [ue, social, ue*social], k-major
  for (int r = g; r < TILE; r += 6) {
    int row = r0 + r;
    float u = aout[((size_t)row << 6) + d];
    float s = sout[((size_t)row << 6) + d];
    As[d][r] = u;
    As[64 + d][r] = s;
    As[128 + d][r] = u * s;
  }
  __syncthreads();

  float4 acc[4];

  // ---- GEMM1: t1 = mish(cat @ W1^T + b1); thread = col jj, rows rr*16..rr*16+15 ----
  #pragma unroll
  for (int q = 0; q < 4; ++q) acc[q] = make_float4(0.f, 0.f, 0.f, 0.f);
  for (int k0 = 0; k0 < KK; k0 += 8) {
    float w[8];
    #pragma unroll
    for (int kk = 0; kk < 8; ++kk) w[kk] = Wt1[(k0 + kk) * KK + jj];
    #pragma unroll
    for (int kk = 0; kk < 8; ++kk) {
      const float4* ar = (const float4*)(&As[k0 + kk][rr * 16]);
      #pragma unroll
      for (int q = 0; q < 4; ++q) {
        float4 a = ar[q];
        acc[q].x = fmaf(a.x, w[kk], acc[q].x);
        acc[q].y = fmaf(a.y, w[kk], acc[q].y);
        acc[q].z = fmaf(a.z, w[kk], acc[q].z);
        acc[q].w = fmaf(a.w, w[kk], acc[q].w);
      }
    }
  }
  {
    float bb = b1[jj];
    __syncthreads();  // all reads of cat done
    #pragma unroll
    for (int q = 0; q < 4; ++q) {
      float4 v;
      v.x = mish_f(acc[q].x + bb);
      v.y = mish_f(acc[q].y + bb);
      v.z = mish_f(acc[q].z + bb);
      v.w = mish_f(acc[q].w + bb);
      *(float4*)(&As[jj][rr * 16 + q * 4]) = v;
    }
  }
  __syncthreads();

  // ---- GEMM2: t2 = mish(t1 @ W2^T + b2) ----
  #pragma unroll
  for (int q = 0; q < 4; ++q) acc[q] = make_float4(0.f, 0.f, 0.f, 0.f);
  for (int k0 = 0; k0 < KK; k0 += 8) {
    float w[8];
    #pragma unroll
    for (int kk = 0; kk < 8; ++kk) w[kk] = Wt2[(k0 + kk) * KK + jj];
    #pragma unroll
    for (int kk = 0; kk < 8; ++kk) {
      const float4* ar = (const float4*)(&As[k0 + kk][rr * 16]);
      #pragma unroll
      for (int q = 0; q < 4; ++q) {
        float4 a = ar[q];
        acc[q].x = fmaf(a.x, w[kk], acc[q].x);
        acc[q].y = fmaf(a.y, w[kk], acc[q].y);
        acc[q].z = fmaf(a.z, w[kk], acc[q].z);
        acc[q].w = fmaf(a.w, w[kk], acc[q].w);
      }
    }
  }
  {
    float bb = b2[jj];
    __syncthreads();
    #pragma unroll
    for (int q = 0; q < 4; ++q) {
      float4 v;
      v.x = mish_f(acc[q].x + bb);
      v.y = mish_f(acc[q].y + bb);
      v.z = mish_f(acc[q].z + bb);
      v.w = mish_f(acc[q].w + bb);
      *(float4*)(&As[jj][rr * 16 + q * 4]) = v;
    }
  }
  __syncthreads();

  // ---- GEMM3: t3 = t2 @ W3^T + b3; lane = col d; 8 row-quads over 6 waves ----
  // wave g owns quad g; waves 0,1 additionally own quads 6,7. Coverage exact, no overlap.
  float4 a30 = make_float4(0.f, 0.f, 0.f, 0.f);
  float4 a31 = make_float4(0.f, 0.f, 0.f, 0.f);
  const bool two = (g < 2);
  for (int k0 = 0; k0 < KK; k0 += 8) {
    float w[8];
    #pragma unroll
    for (int kk = 0; kk < 8; ++kk) w[kk] = Wt3[(k0 + kk) * DN + d];
    #pragma unroll
    for (int kk = 0; kk < 8; ++kk) {
      const float* rowp = &As[k0 + kk][0];
      float4 a = *(const float4*)(rowp + g * 4);
      a30.x = fmaf(a.x, w[kk], a30.x);
      a30.y = fmaf(a.y, w[kk], a30.y);
      a30.z = fmaf(a.z, w[kk], a30.z);
      a30.w = fmaf(a.w, w[kk], a30.w);
      if (two) {
        float4 b = *(const float4*)(rowp + (6 + g) * 4);
        a31.x = fmaf(b.x, w[kk], a31.x);
        a31.y = fmaf(b.y, w[kk], a31.y);
        a31.z = fmaf(b.z, w[kk], a31.z);
        a31.w = fmaf(b.w, w[kk], a31.w);
      }
    }
  }
  float b3v = b3[d];
  float lss = 0.f;
  {
    int rbase = r0 + g * 4;
    float4 v;
    v.x = a30.x + b3v; v.y = a30.y + b3v; v.z = a30.z + b3v; v.w = a30.w + b3v;
    t3out[((size_t)(rbase + 0) << 6) + d] = v.x; lss = fmaf(v.x, v.x, lss);
    t3out[((size_t)(rbase + 1) << 6) + d] = v.y; lss = fmaf(v.y, v.y, lss);
    t3out[((size_t)(rbase + 2) << 6) + d] = v.z; lss = fmaf(v.z, v.z, lss);
    t3out[((size_t)(rbase + 3) << 6) + d] = v.w; lss = fmaf(v.w, v.w, lss);
  }
  if (two) {
    int rbase = r0 + (6 + g) * 4;
    float4 v;
    v.x = a31.x + b3v; v.y = a31.y + b3v; v.z = a31.z + b3v; v.w = a31.w + b3v;
    t3out[((size_t)(rbase + 0) << 6) + d] = v.x; lss = fmaf(v.x, v.x, lss);
    t3out[((size_t)(rbase + 1) << 6) + d] = v.y; lss = fmaf(v.y, v.y, lss);
    t3out[((size_t)(rbase + 2) << 6) + d] = v.z; lss = fmaf(v.z, v.z, lss);
    t3out[((size_t)(rbase + 3) << 6) + d] = v.w; lss = fmaf(v.w, v.w, lss);
  }
  #pragma unroll
  for (int off = 32; off > 0; off >>= 1) lss += __shfl_down(lss, off);
  if (d == 0) ssred[g] = lss;
  __syncthreads();
  if (tid == 0) {
    float s = 0.f;
    #pragma unroll
    for (int i = 0; i < 6; ++i) s += ssred[i];
    atomicAdd(sumsq, s);
  }
}

__global__ void finalize_kernel(const float* __restrict__ t3, const float* __restrict__ sumsq,
                                const float* __restrict__ aout, ushort* __restrict__ egoh,
                                float* __restrict__ outacc, int last) {
  size_t i = (size_t)blockIdx.x * blockDim.x + threadIdx.x;
  size_t total = (size_t)UIN * DN;
  if (i >= total) return;
  size_t usz = (size_t)UN * DN;
  float v;
  if (i < usz) {
    float inv = 1.0f / sqrtf(sumsq[0]);
    v = t3[i] * inv;
  } else {
    v = aout[i];
  }
  if (last) {
    outacc[i] = (outacc[i] + v) * 0.25f;
  } else {
    egoh[i] = f2bf(v);
    outacc[i] += v;
  }
}

extern "C" void kernel_launch(void* const* d_in, const int* in_sizes, int n_in,
                              void* d_out, int out_size, void* d_ws, size_t ws_size,
                              hipStream_t stream) {
  const float* user_emb = (const float*)d_in[0];
  const float* item_emb = (const float*)d_in[1];
  const int* A_rows = (const int*)d_in[2];
  const int* A_cols = (const int*)d_in[3];
  const float* A_vals = (const float*)d_in[4];
  const int* S_rows = (const int*)d_in[5];
  const int* S_cols = (const int*)d_in[6];
  const float* S_vals = (const float*)d_in[7];
  const float* W1 = (const float*)d_in[8];
  const float* b1 = (const float*)d_in[9];
  const float* W2 = (const float*)d_in[10];
  const float* b2 = (const float*)d_in[11];
  const float* W3 = (const float*)d_in[12];
  const float* b3 = (const float*)d_in[13];
  const int nnzA = in_sizes[2];
  const int nnzS = in_sizes[5];

  float* ws = (float*)d_ws;
  size_t off = 0;
  ushort* egoh = (ushort*)(ws + off); off += (size_t)UIN * DN / 2;  // bf16 mirror
  float* aout = ws + off; off += (size_t)UIN * DN;
  float* sout = ws + off; off += (size_t)UN * DN;   // also aliased as t3 (per-block read-then-write)
  float* ss = ws + off;   off += 16;
  float* Wt1 = ws + off;  off += KK * KK;
  float* Wt2 = ws + off;  off += KK * KK;
  float* Wt3 = ws + off;  off += KK * DN;
  int* cntA = (int*)(ws + off);  off += UIN;   // cntA+cntS contiguous for one memset
  int* cntS = (int*)(ws + off);  off += UN;
  int* rptrA = (int*)(ws + off); off += UIN + 1;
  int* tmpA = (int*)(ws + off);  off += UIN;
  int* rptrS = (int*)(ws + off); off += UN + 1;
  int* tmpS = (int*)(ws + off);  off += UN;
  off = (off + 1) & ~(size_t)1;  // 8B align
  int2* pA = (int2*)(ws + off);  off += (size_t)2 * nnzA;
  int2* pS = (int2*)(ws + off);  off += (size_t)2 * nnzS;
  float* outacc = (float*)d_out;
  float* t3 = sout;

  const size_t total = (size_t)UIN * DN;
  const int nblk_elem = (int)((total + 255) / 256);

  // CSR build (every call; ws is re-poisoned before each timed launch)
  hipMemsetAsync(cntA, 0, (size_t)(UIN + UN) * sizeof(int), stream);
  hist_kernel<<<(nnzA + 255) / 256, 256, 0, stream>>>(A_rows, cntA, nnzA);
  hist_kernel<<<(nnzS + 255) / 256, 256, 0, stream>>>(S_rows, cntS, nnzS);
  scan_kernel<<<1, 1024, 0, stream>>>(cntA, rptrA, tmpA, UIN);
  scan_kernel<<<1, 1024, 0, stream>>>(cntS, rptrS, tmpS, UN);
  scatter_kernel<<<(nnzA + 255) / 256, 256, 0, stream>>>(A_rows, A_cols, A_vals, tmpA, pA, nnzA);
  scatter_kernel<<<(nnzS + 255) / 256, 256, 0, stream>>>(S_rows, S_cols, S_vals, tmpS, pS, nnzS);

  init_kernel<<<nblk_elem, 256, 0, stream>>>(user_emb, item_emb, egoh, outacc);
  transpose_w<<<(KK * KK + 255) / 256, 256, 0, stream>>>(W1, Wt1, KK, KK);
  transpose_w<<<(KK * KK + 255) / 256, 256, 0, stream>>>(W2, Wt2, KK, KK);
  transpose_w<<<(KK * DN + 255) / 256, 256, 0, stream>>>(W3, Wt3, DN, KK);

  for (int layer = 0; layer < 3; ++layer) {
    hipMemsetAsync(ss, 0, 64, stream);
    spmm_csr<<<(UIN + 3) / 4, 256, 0, stream>>>(rptrA, pA, egoh, aout, UIN);
    spmm_csr<<<(UN + 3) / 4, 256, 0, stream>>>(rptrS, pS, egoh, sout, UN);
    fusion_kernel<<<UN / TILE, 384, 0, stream>>>(aout, sout, Wt1, b1, Wt2, b2, Wt3, b3, t3, ss);
    finalize_kernel<<<nblk_elem, 256, 0, stream>>>(t3, ss, aout, egoh, outacc, layer == 2);
  }
}

// Round 8
// 2068.309 us; speedup vs baseline: 1.6420x; 1.2588x over previous
//
#include <hip/hip_runtime.h>

#define UN 100000
#define INN 50000
#define UIN 150000
#define DN 64
#define KK 192
#define TILE 32
#define LPAD 200  // ushort cols per LDS row: 400B stride, 16B-aligned, <=2-way banks

typedef __attribute__((ext_vector_type(8))) short bf16x8;
typedef __attribute__((ext_vector_type(4))) float f32x4;

// mish(x) = x * (t^2 + 2t) / (t^2 + 2t + 2), t = e^x
__device__ __forceinline__ float mish_f(float x) {
  float t = __expf(x);
  float num = fmaf(t, t, 2.0f * t);
  float m = x * num / (num + 2.0f);
  return (x > 20.0f) ? x : m;
}

__device__ __forceinline__ float bf2f(ushort u) {
  return __uint_as_float(((unsigned int)u) << 16);
}
__device__ __forceinline__ ushort f2bf(float f) {  // RNE
  unsigned int u = __float_as_uint(f);
  u += 0x7FFFu + ((u >> 16) & 1u);
  return (ushort)(u >> 16);
}

__global__ void init_kernel(const float* __restrict__ ue, const float* __restrict__ ie,
                            ushort* __restrict__ egoh, float* __restrict__ outacc) {
  size_t i = (size_t)blockIdx.x * blockDim.x + threadIdx.x;
  size_t total = (size_t)UIN * DN;
  if (i >= total) return;
  size_t usz = (size_t)UN * DN;
  float v = (i < usz) ? ue[i] : ie[i - usz];
  egoh[i] = f2bf(v);
  outacc[i] = v;
}

__global__ void convert_w(const float* __restrict__ W, ushort* __restrict__ Wb, int n) {
  int i = blockIdx.x * blockDim.x + threadIdx.x;
  if (i < n) Wb[i] = f2bf(W[i]);
}

// ---------------- CSR build (row lists padded to multiple of 4) ----------------
__global__ void hist_kernel(const int* __restrict__ rows, int* __restrict__ cnt, int nnz) {
  int e = blockIdx.x * blockDim.x + threadIdx.x;
  if (e < nnz) atomicAdd(&cnt[rows[e]], 1);
}

__global__ __launch_bounds__(1024) void scan_kernel(const int* __restrict__ cnt,
                                                    int* __restrict__ rowptr,
                                                    int* __restrict__ tmp, int n) {
  __shared__ int part[1024];
  int tid = threadIdx.x;
  int per = (n + 1023) >> 10;
  int start = tid * per;
  int end = min(start + per, n);
  int s = 0;
  for (int i = start; i < end; ++i) s += (cnt[i] + 3) & ~3;
  part[tid] = s;
  __syncthreads();
  for (int off = 1; off < 1024; off <<= 1) {
    int v = (tid >= off) ? part[tid - off] : 0;
    __syncthreads();
    part[tid] += v;
    __syncthreads();
  }
  int run = (tid == 0) ? 0 : part[tid - 1];
  for (int i = start; i < end; ++i) {
    rowptr[i] = run;
    tmp[i] = run;
    run += (cnt[i] + 3) & ~3;
  }
  if (start < n && end == n) rowptr[n] = run;
}

__global__ void scatter_kernel(const int* __restrict__ rows, const int* __restrict__ cols,
                               const float* __restrict__ vals, int* __restrict__ tmp,
                               int2* __restrict__ packed, int nnz) {
  int e = blockIdx.x * blockDim.x + threadIdx.x;
  if (e >= nnz) return;
  int pos = atomicAdd(&tmp[rows[e]], 1);
  packed[pos] = make_int2(cols[e], __float_as_int(vals[e]));
}

// ---------------- SpMM: wave = 1 row, 16 lanes/row-slice, 4 edges per step ----------------
__global__ __launch_bounds__(256) void spmm4(const int* __restrict__ rowptr,
                                             const int2* __restrict__ packed,
                                             const ushort* __restrict__ xh,
                                             float* __restrict__ out, int nrows) {
  int r = blockIdx.x * 4 + (threadIdx.x >> 6);
  if (r >= nrows) return;
  int l = threadIdx.x & 63;
  int sub = l >> 4;        // edge slot 0..3
  int c16 = l & 15;        // feature group (4 bf16)
  int beg = rowptr[r], end = rowptr[r + 1];  // count is multiple of 4 (padded, val=0)
  float4 acc = make_float4(0.f, 0.f, 0.f, 0.f);
  float4 acc2 = make_float4(0.f, 0.f, 0.f, 0.f);
  int e = beg + sub;
  for (; e + 4 < end; e += 8) {
    int2 p0 = packed[e];
    int2 p1 = packed[e + 4];
    ushort4 x0 = *(const ushort4*)(xh + (((size_t)p0.x) << 6) + (c16 << 2));
    ushort4 x1 = *(const ushort4*)(xh + (((size_t)p1.x) << 6) + (c16 << 2));
    float v0 = __int_as_float(p0.y);
    float v1 = __int_as_float(p1.y);
    acc.x = fmaf(v0, bf2f(x0.x), acc.x);
    acc.y = fmaf(v0, bf2f(x0.y), acc.y);
    acc.z = fmaf(v0, bf2f(x0.z), acc.z);
    acc.w = fmaf(v0, bf2f(x0.w), acc.w);
    acc2.x = fmaf(v1, bf2f(x1.x), acc2.x);
    acc2.y = fmaf(v1, bf2f(x1.y), acc2.y);
    acc2.z = fmaf(v1, bf2f(x1.z), acc2.z);
    acc2.w = fmaf(v1, bf2f(x1.w), acc2.w);
  }
  if (e < end) {
    int2 p = packed[e];
    ushort4 xv = *(const ushort4*)(xh + (((size_t)p.x) << 6) + (c16 << 2));
    float v = __int_as_float(p.y);
    acc.x = fmaf(v, bf2f(xv.x), acc.x);
    acc.y = fmaf(v, bf2f(xv.y), acc.y);
    acc.z = fmaf(v, bf2f(xv.z), acc.z);
    acc.w = fmaf(v, bf2f(xv.w), acc.w);
  }
  acc.x += acc2.x; acc.y += acc2.y; acc.z += acc2.z; acc.w += acc2.w;
  acc.x += __shfl_xor(acc.x, 16); acc.y += __shfl_xor(acc.y, 16);
  acc.z += __shfl_xor(acc.z, 16); acc.w += __shfl_xor(acc.w, 16);
  acc.x += __shfl_xor(acc.x, 32); acc.y += __shfl_xor(acc.y, 32);
  acc.z += __shfl_xor(acc.z, 32); acc.w += __shfl_xor(acc.w, 32);
  if (sub == 0) *(float4*)(out + (((size_t)r) << 6) + (c16 << 2)) = acc;
}

// ---------------- Fused 3-GEMM MLP via MFMA, 256 threads, 32-row tile ----------------
// mfma_f32_16x16x32_bf16: A lane l: row=l&15, k=(l>>4)*8+r ; B lane l: col=l&15, k=(l>>4)*8+r
// D lane l: col=l&15, row=(l>>4)*4+reg  [m89/m91 verified]
__global__ __launch_bounds__(256) void fusion_mfma(
    const float* __restrict__ aout, const float* __restrict__ sout,
    const ushort* __restrict__ Wb1, const float* __restrict__ b1,
    const ushort* __restrict__ Wb2, const float* __restrict__ b2,
    const ushort* __restrict__ Wb3, const float* __restrict__ b3,
    float* __restrict__ t3out, float* __restrict__ sumsq) {
  __shared__ ushort bufA[TILE][LPAD];  // cat, later t2
  __shared__ ushort bufB[TILE][LPAD];  // t1
  __shared__ float ssred[4];
  const int tid = threadIdx.x;
  const int w = tid >> 6;      // wave 0..3
  const int l = tid & 63;
  const int lg = l >> 4;       // lane group 0..3
  const int lr = l & 15;
  const int mt = w & 1;        // M-tile of this wave
  const int wn = w >> 1;       // N-tile parity
  const int r0 = blockIdx.x * TILE;  // UN = 3125*32

  // ---- stage cat = [u, s, u*s] as bf16, row-major [32][192] ----
  {
    int row = tid >> 3;
    int c0 = (tid & 7) * 8;
    const float4* ap = (const float4*)(aout + (((size_t)(r0 + row)) << 6) + c0);
    const float4* sp = (const float4*)(sout + (((size_t)(r0 + row)) << 6) + c0);
    float4 u0 = ap[0], u1 = ap[1];
    float4 s0 = sp[0], s1 = sp[1];
    float uu[8] = {u0.x, u0.y, u0.z, u0.w, u1.x, u1.y, u1.z, u1.w};
    float ssv[8] = {s0.x, s0.y, s0.z, s0.w, s1.x, s1.y, s1.z, s1.w};
    bf16x8 vu, vs, vm;
    #pragma unroll
    for (int j = 0; j < 8; ++j) {
      vu[j] = (short)f2bf(uu[j]);
      vs[j] = (short)f2bf(ssv[j]);
      vm[j] = (short)f2bf(uu[j] * ssv[j]);
    }
    *(bf16x8*)&bufA[row][c0] = vu;
    *(bf16x8*)&bufA[row][64 + c0] = vs;
    *(bf16x8*)&bufA[row][128 + c0] = vm;
  }
  __syncthreads();

  f32x4 acc[6];
  bf16x8 areg[6];

  // ---- GEMM1: t1 = mish(cat @ W1^T + b1) -> bufB ----
  #pragma unroll
  for (int kt = 0; kt < 6; ++kt)
    areg[kt] = *(const bf16x8*)&bufA[(mt << 4) + lr][lg * 8 + kt * 32];
  #pragma unroll
  for (int t = 0; t < 6; ++t) acc[t] = (f32x4){0.f, 0.f, 0.f, 0.f};
  #pragma unroll
  for (int kt = 0; kt < 6; ++kt) {
    #pragma unroll
    for (int t = 0; t < 6; ++t) {
      int n = (wn + 2 * t) * 16 + lr;
      bf16x8 b = *(const bf16x8*)(Wb1 + (size_t)n * KK + lg * 8 + kt * 32);
      acc[t] = __builtin_amdgcn_mfma_f32_16x16x32_bf16(areg[kt], b, acc[t], 0, 0, 0);
    }
  }
  #pragma unroll
  for (int t = 0; t < 6; ++t) {
    int n = (wn + 2 * t) * 16 + lr;
    float bias = b1[n];
    int rowb = (mt << 4) + (lg << 2);
    #pragma unroll
    for (int q = 0; q < 4; ++q)
      bufB[rowb + q][n] = f2bf(mish_f(acc[t][q] + bias));
  }
  __syncthreads();

  // ---- GEMM2: t2 = mish(t1 @ W2^T + b2) -> bufA ----
  #pragma unroll
  for (int kt = 0; kt < 6; ++kt)
    areg[kt] = *(const bf16x8*)&bufB[(mt << 4) + lr][lg * 8 + kt * 32];
  #pragma unroll
  for (int t = 0; t < 6; ++t) acc[t] = (f32x4){0.f, 0.f, 0.f, 0.f};
  #pragma unroll
  for (int kt = 0; kt < 6; ++kt) {
    #pragma unroll
    for (int t = 0; t < 6; ++t) {
      int n = (wn + 2 * t) * 16 + lr;
      bf16x8 b = *(const bf16x8*)(Wb2 + (size_t)n * KK + lg * 8 + kt * 32);
      acc[t] = __builtin_amdgcn_mfma_f32_16x16x32_bf16(areg[kt], b, acc[t], 0, 0, 0);
    }
  }
  __syncthreads();  // all reads of bufA (GEMM1 aregs long done) + ensure bufB reads done before overwrite? bufA writes next
  #pragma unroll
  for (int t = 0; t < 6; ++t) {
    int n = (wn + 2 * t) * 16 + lr;
    float bias = b2[n];
    int rowb = (mt << 4) + (lg << 2);
    #pragma unroll
    for (int q = 0; q < 4; ++q)
      bufA[rowb + q][n] = f2bf(mish_f(acc[t][q] + bias));
  }
  __syncthreads();

  // ---- GEMM3: t3 = t2 @ W3^T + b3 -> global + sumsq ----
  #pragma unroll
  for (int kt = 0; kt < 6; ++kt)
    areg[kt] = *(const bf16x8*)&bufA[(mt << 4) + lr][lg * 8 + kt * 32];
  f32x4 a3[2];
  a3[0] = (f32x4){0.f, 0.f, 0.f, 0.f};
  a3[1] = (f32x4){0.f, 0.f, 0.f, 0.f};
  #pragma unroll
  for (int kt = 0; kt < 6; ++kt) {
    #pragma unroll
    for (int t = 0; t < 2; ++t) {
      int n = (wn + 2 * t) * 16 + lr;
      bf16x8 b = *(const bf16x8*)(Wb3 + (size_t)n * KK + lg * 8 + kt * 32);
      a3[t] = __builtin_amdgcn_mfma_f32_16x16x32_bf16(areg[kt], b, a3[t], 0, 0, 0);
    }
  }
  float lss = 0.f;
  #pragma unroll
  for (int t = 0; t < 2; ++t) {
    int n = (wn + 2 * t) * 16 + lr;
    float bias = b3[n];
    int rowb = r0 + (mt << 4) + (lg << 2);
    #pragma unroll
    for (int q = 0; q < 4; ++q) {
      float v = a3[t][q] + bias;
      t3out[(((size_t)(rowb + q)) << 6) + n] = v;
      lss = fmaf(v, v, lss);
    }
  }
  #pragma unroll
  for (int off = 32; off > 0; off >>= 1) lss += __shfl_down(lss, off);
  if (l == 0) ssred[w] = lss;
  __syncthreads();
  if (tid == 0) atomicAdd(sumsq, ssred[0] + ssred[1] + ssred[2] + ssred[3]);
}

__global__ void finalize_kernel(const float* __restrict__ t3, const float* __restrict__ sumsq,
                                const float* __restrict__ aout, ushort* __restrict__ egoh,
                                float* __restrict__ outacc, int last) {
  size_t i = (size_t)blockIdx.x * blockDim.x + threadIdx.x;
  size_t total = (size_t)UIN * DN;
  if (i >= total) return;
  size_t usz = (size_t)UN * DN;
  float v;
  if (i < usz) {
    float inv = 1.0f / sqrtf(sumsq[0]);
    v = t3[i] * inv;
  } else {
    v = aout[i];
  }
  if (last) {
    outacc[i] = (outacc[i] + v) * 0.25f;
  } else {
    egoh[i] = f2bf(v);
    outacc[i] += v;
  }
}

extern "C" void kernel_launch(void* const* d_in, const int* in_sizes, int n_in,
                              void* d_out, int out_size, void* d_ws, size_t ws_size,
                              hipStream_t stream) {
  const float* user_emb = (const float*)d_in[0];
  const float* item_emb = (const float*)d_in[1];
  const int* A_rows = (const int*)d_in[2];
  const int* A_cols = (const int*)d_in[3];
  const float* A_vals = (const float*)d_in[4];
  const int* S_rows = (const int*)d_in[5];
  const int* S_cols = (const int*)d_in[6];
  const float* S_vals = (const float*)d_in[7];
  const float* W1 = (const float*)d_in[8];
  const float* b1 = (const float*)d_in[9];
  const float* W2 = (const float*)d_in[10];
  const float* b2 = (const float*)d_in[11];
  const float* W3 = (const float*)d_in[12];
  const float* b3 = (const float*)d_in[13];
  const int nnzA = in_sizes[2];
  const int nnzS = in_sizes[5];

  float* ws = (float*)d_ws;
  size_t off = 0;
  ushort* egoh = (ushort*)(ws + off); off += (size_t)UIN * DN / 2;  // bf16 embeddings
  float* aout = ws + off; off += (size_t)UIN * DN;
  float* sout = ws + off; off += (size_t)UN * DN;   // aliased as t3 (per-block read-then-write)
  float* ss = ws + off;   off += 16;
  ushort* Wb1 = (ushort*)(ws + off); off += KK * KK / 2;
  ushort* Wb2 = (ushort*)(ws + off); off += KK * KK / 2;
  ushort* Wb3 = (ushort*)(ws + off); off += KK * DN / 2;
  int* cntA = (int*)(ws + off);  off += UIN;   // cntA+cntS contiguous for one memset
  int* cntS = (int*)(ws + off);  off += UN;
  int* rptrA = (int*)(ws + off); off += UIN + 1;
  int* tmpA = (int*)(ws + off);  off += UIN;
  int* rptrS = (int*)(ws + off); off += UN + 1;
  int* tmpS = (int*)(ws + off);  off += UN;
  off = (off + 1) & ~(size_t)1;  // 8B align
  const size_t padA = (size_t)nnzA + 4 * UIN;
  const size_t padS = (size_t)nnzS + 4 * UN;
  int2* pA = (int2*)(ws + off);  off += 2 * padA;
  int2* pS = (int2*)(ws + off);  off += 2 * padS;
  float* outacc = (float*)d_out;
  float* t3 = sout;

  const size_t total = (size_t)UIN * DN;
  const int nblk_elem = (int)((total + 255) / 256);

  // CSR build: counts -> padded scan -> scatter (padding slots stay {col=0,val=0})
  hipMemsetAsync(cntA, 0, (size_t)(UIN + UN) * sizeof(int), stream);
  hipMemsetAsync(pA, 0, (padA + padS) * sizeof(int2), stream);
  hist_kernel<<<(nnzA + 255) / 256, 256, 0, stream>>>(A_rows, cntA, nnzA);
  hist_kernel<<<(nnzS + 255) / 256, 256, 0, stream>>>(S_rows, cntS, nnzS);
  scan_kernel<<<1, 1024, 0, stream>>>(cntA, rptrA, tmpA, UIN);
  scan_kernel<<<1, 1024, 0, stream>>>(cntS, rptrS, tmpS, UN);
  scatter_kernel<<<(nnzA + 255) / 256, 256, 0, stream>>>(A_rows, A_cols, A_vals, tmpA, pA, nnzA);
  scatter_kernel<<<(nnzS + 255) / 256, 256, 0, stream>>>(S_rows, S_cols, S_vals, tmpS, pS, nnzS);

  init_kernel<<<nblk_elem, 256, 0, stream>>>(user_emb, item_emb, egoh, outacc);
  convert_w<<<(KK * KK + 255) / 256, 256, 0, stream>>>(W1, Wb1, KK * KK);
  convert_w<<<(KK * KK + 255) / 256, 256, 0, stream>>>(W2, Wb2, KK * KK);
  convert_w<<<(KK * DN + 255) / 256, 256, 0, stream>>>(W3, Wb3, KK * DN);

  for (int layer = 0; layer < 3; ++layer) {
    hipMemsetAsync(ss, 0, 64, stream);
    spmm4<<<(UIN + 3) / 4, 256, 0, stream>>>(rptrA, pA, egoh, aout, UIN);
    spmm4<<<(UN + 3) / 4, 256, 0, stream>>>(rptrS, pS, egoh, sout, UN);
    fusion_mfma<<<UN / TILE, 256, 0, stream>>>(aout, sout, Wb1, b1, Wb2, b2, Wb3, b3, t3, ss);
    finalize_kernel<<<nblk_elem, 256, 0, stream>>>(t3, ss, aout, egoh, outacc, layer == 2);
  }
}

// Round 11
// 1497.569 us; speedup vs baseline: 2.2679x; 1.3811x over previous
//
#include <hip/hip_runtime.h>

#define UN 100000
#define INN 50000
#define UIN 150000
#define DN 64
#define KK 192
#define TILE 32
#define LPAD 200  // ushort cols per LDS row: 400B stride, 16B-aligned, <=2-way banks
#define NROWS_ALL (UIN + UN)

typedef __attribute__((ext_vector_type(8))) short bf16x8;
typedef __attribute__((ext_vector_type(4))) float f32x4;

// mish(x) = x * (t^2 + 2t) / (t^2 + 2t + 2), t = e^x
__device__ __forceinline__ float mish_f(float x) {
  float t = __expf(x);
  float num = fmaf(t, t, 2.0f * t);
  float m = x * num / (num + 2.0f);
  return (x > 20.0f) ? x : m;
}

__device__ __forceinline__ float bf2f(ushort u) {
  return __uint_as_float(((unsigned int)u) << 16);
}
__device__ __forceinline__ ushort f2bf(float f) {  // RNE
  unsigned int u = __float_as_uint(f);
  u += 0x7FFFu + ((u >> 16) & 1u);
  return (ushort)(u >> 16);
}

__global__ void init_kernel(const float* __restrict__ ue, const float* __restrict__ ie,
                            ushort* __restrict__ egoh, float* __restrict__ outacc) {
  size_t i = (size_t)blockIdx.x * blockDim.x + threadIdx.x;
  size_t total = (size_t)UIN * DN;
  if (i >= total) return;
  size_t usz = (size_t)UN * DN;
  float v = (i < usz) ? ue[i] : ie[i - usz];
  egoh[i] = f2bf(v);
  outacc[i] = v;
}

__global__ void convert_w(const float* __restrict__ W, ushort* __restrict__ Wb, int n) {
  int i = blockIdx.x * blockDim.x + threadIdx.x;
  if (i < n) Wb[i] = f2bf(W[i]);
}

// ---------------- CSR build: combined A(+0) and S(+UIN) rows, lists padded to x4 ----------------
__global__ void hist_kernel(const int* __restrict__ rows, int* __restrict__ cnt, int nnz) {
  int e = blockIdx.x * blockDim.x + threadIdx.x;
  if (e < nnz) atomicAdd(&cnt[rows[e]], 1);
}

// level 0: per-block (256) inclusive scan of padded counts -> exclusive offsets + block sums
__global__ __launch_bounds__(256) void scan1(const int* __restrict__ cnt,
                                             int* __restrict__ rowptr,  // [i] = excl offset within block
                                             int* __restrict__ bsum, int n) {
  __shared__ int sh[256];
  int i = blockIdx.x * 256 + threadIdx.x;
  int v = (i < n) ? ((cnt[i] + 3) & ~3) : 0;
  sh[threadIdx.x] = v;
  __syncthreads();
  #pragma unroll
  for (int off = 1; off < 256; off <<= 1) {
    int t = (threadIdx.x >= off) ? sh[threadIdx.x - off] : 0;
    __syncthreads();
    sh[threadIdx.x] += t;
    __syncthreads();
  }
  if (i < n) rowptr[i] = sh[threadIdx.x] - v;
  if (threadIdx.x == 255) bsum[blockIdx.x] = sh[255];
}

// level 1: single-block scan of block sums (nb <= 1024)
__global__ __launch_bounds__(1024) void scan2(int* __restrict__ bsum, int nb) {
  __shared__ int sh[1024];
  int tid = threadIdx.x;
  int v = (tid < nb) ? bsum[tid] : 0;
  sh[tid] = v;
  __syncthreads();
  #pragma unroll
  for (int off = 1; off < 1024; off <<= 1) {
    int t = (tid >= off) ? sh[tid - off] : 0;
    __syncthreads();
    sh[tid] += t;
    __syncthreads();
  }
  if (tid < nb) bsum[tid] = sh[tid] - v;  // exclusive
}

// level 2: add block offsets; produce rowptr + scatter cursors + final total
__global__ void scan3(int* __restrict__ rowptr, const int* __restrict__ bsum,
                      const int* __restrict__ cnt, int* __restrict__ tmp, int n) {
  int i = blockIdx.x * 256 + threadIdx.x;
  if (i >= n) return;
  int r = rowptr[i] + bsum[i >> 8];
  rowptr[i] = r;
  tmp[i] = r;
  if (i == n - 1) rowptr[n] = r + ((cnt[i] + 3) & ~3);
}

__global__ void scatter_kernel(const int* __restrict__ rows, const int* __restrict__ cols,
                               const float* __restrict__ vals, int* __restrict__ tmp,
                               int2* __restrict__ packed, int nnz) {
  int e = blockIdx.x * blockDim.x + threadIdx.x;
  if (e >= nnz) return;
  int pos = atomicAdd(&tmp[rows[e]], 1);
  packed[pos] = make_int2(cols[e], __float_as_int(vals[e]));
}

// ---------------- SpMM: wave = 1 row, 16 lanes/row-slice, 4 edge slots, 4-deep ILP ----------------
__global__ __launch_bounds__(256) void spmm4(const int* __restrict__ rowptr,
                                             const int2* __restrict__ packed,
                                             const ushort* __restrict__ xh,
                                             float* __restrict__ out, int nrows) {
  int r = blockIdx.x * 4 + (threadIdx.x >> 6);
  if (r >= nrows) return;
  int l = threadIdx.x & 63;
  int sub = l >> 4;        // edge slot 0..3
  int c16 = l & 15;        // feature group (4 bf16)
  int beg = rowptr[r], end = rowptr[r + 1];  // count multiple of 4 (padded, val=0)
  float4 A0 = make_float4(0.f, 0.f, 0.f, 0.f);
  float4 A1 = make_float4(0.f, 0.f, 0.f, 0.f);
  float4 A2 = make_float4(0.f, 0.f, 0.f, 0.f);
  float4 A3 = make_float4(0.f, 0.f, 0.f, 0.f);
  int e = beg + sub;
  for (; e + 12 < end; e += 16) {
    int2 p0 = packed[e];
    int2 p1 = packed[e + 4];
    int2 p2 = packed[e + 8];
    int2 p3 = packed[e + 12];
    ushort4 x0 = *(const ushort4*)(xh + (((size_t)p0.x) << 6) + (c16 << 2));
    ushort4 x1 = *(const ushort4*)(xh + (((size_t)p1.x) << 6) + (c16 << 2));
    ushort4 x2 = *(const ushort4*)(xh + (((size_t)p2.x) << 6) + (c16 << 2));
    ushort4 x3 = *(const ushort4*)(xh + (((size_t)p3.x) << 6) + (c16 << 2));
    float v0 = __int_as_float(p0.y);
    float v1 = __int_as_float(p1.y);
    float v2 = __int_as_float(p2.y);
    float v3 = __int_as_float(p3.y);
    A0.x = fmaf(v0, bf2f(x0.x), A0.x); A0.y = fmaf(v0, bf2f(x0.y), A0.y);
    A0.z = fmaf(v0, bf2f(x0.z), A0.z); A0.w = fmaf(v0, bf2f(x0.w), A0.w);
    A1.x = fmaf(v1, bf2f(x1.x), A1.x); A1.y = fmaf(v1, bf2f(x1.y), A1.y);
    A1.z = fmaf(v1, bf2f(x1.z), A1.z); A1.w = fmaf(v1, bf2f(x1.w), A1.w);
    A2.x = fmaf(v2, bf2f(x2.x), A2.x); A2.y = fmaf(v2, bf2f(x2.y), A2.y);
    A2.z = fmaf(v2, bf2f(x2.z), A2.z); A2.w = fmaf(v2, bf2f(x2.w), A2.w);
    A3.x = fmaf(v3, bf2f(x3.x), A3.x); A3.y = fmaf(v3, bf2f(x3.y), A3.y);
    A3.z = fmaf(v3, bf2f(x3.z), A3.z); A3.w = fmaf(v3, bf2f(x3.w), A3.w);
  }
  for (; e < end; e += 4) {
    int2 p = packed[e];
    ushort4 xv = *(const ushort4*)(xh + (((size_t)p.x) << 6) + (c16 << 2));
    float v = __int_as_float(p.y);
    A0.x = fmaf(v, bf2f(xv.x), A0.x); A0.y = fmaf(v, bf2f(xv.y), A0.y);
    A0.z = fmaf(v, bf2f(xv.z), A0.z); A0.w = fmaf(v, bf2f(xv.w), A0.w);
  }
  A0.x += A1.x + A2.x + A3.x;
  A0.y += A1.y + A2.y + A3.y;
  A0.z += A1.z + A2.z + A3.z;
  A0.w += A1.w + A2.w + A3.w;
  A0.x += __shfl_xor(A0.x, 16); A0.y += __shfl_xor(A0.y, 16);
  A0.z += __shfl_xor(A0.z, 16); A0.w += __shfl_xor(A0.w, 16);
  A0.x += __shfl_xor(A0.x, 32); A0.y += __shfl_xor(A0.y, 32);
  A0.z += __shfl_xor(A0.z, 32); A0.w += __shfl_xor(A0.w, 32);
  if (sub == 0) *(float4*)(out + (((size_t)r) << 6) + (c16 << 2)) = A0;
}

// ---------------- Fused 3-GEMM MLP via MFMA, 256 threads, 32-row tile ----------------
// mfma_f32_16x16x32_bf16: A lane l: row=l&15, k=(l>>4)*8+r ; B lane l: col=l&15, k=(l>>4)*8+r
// D lane l: col=l&15, row=(l>>4)*4+reg  [m89/m91 verified]
__global__ __launch_bounds__(256) void fusion_mfma(
    const float* __restrict__ aout, const float* __restrict__ sout,
    const ushort* __restrict__ Wb1, const float* __restrict__ b1,
    const ushort* __restrict__ Wb2, const float* __restrict__ b2,
    const ushort* __restrict__ Wb3, const float* __restrict__ b3,
    float* __restrict__ t3out, float* __restrict__ sumsq) {
  __shared__ ushort bufA[TILE][LPAD];  // cat, later t2
  __shared__ ushort bufB[TILE][LPAD];  // t1
  __shared__ float ssred[4];
  const int tid = threadIdx.x;
  const int w = tid >> 6;      // wave 0..3
  const int l = tid & 63;
  const int lg = l >> 4;       // lane group 0..3
  const int lr = l & 15;
  const int mt = w & 1;        // M-tile of this wave
  const int wn = w >> 1;       // N-tile parity
  const int r0 = blockIdx.x * TILE;  // UN = 3125*32

  // ---- stage cat = [u, s, u*s] as bf16, row-major [32][192] ----
  {
    int row = tid >> 3;
    int c0 = (tid & 7) * 8;
    const float4* ap = (const float4*)(aout + (((size_t)(r0 + row)) << 6) + c0);
    const float4* sp = (const float4*)(sout + (((size_t)(r0 + row)) << 6) + c0);
    float4 u0 = ap[0], u1 = ap[1];
    float4 s0 = sp[0], s1 = sp[1];
    float uu[8] = {u0.x, u0.y, u0.z, u0.w, u1.x, u1.y, u1.z, u1.w};
    float ssv[8] = {s0.x, s0.y, s0.z, s0.w, s1.x, s1.y, s1.z, s1.w};
    bf16x8 vu, vs, vm;
    #pragma unroll
    for (int j = 0; j < 8; ++j) {
      vu[j] = (short)f2bf(uu[j]);
      vs[j] = (short)f2bf(ssv[j]);
      vm[j] = (short)f2bf(uu[j] * ssv[j]);
    }
    *(bf16x8*)&bufA[row][c0] = vu;
    *(bf16x8*)&bufA[row][64 + c0] = vs;
    *(bf16x8*)&bufA[row][128 + c0] = vm;
  }
  __syncthreads();

  f32x4 acc[6];
  bf16x8 areg[6];

  // ---- GEMM1: t1 = mish(cat @ W1^T + b1) -> bufB ----
  #pragma unroll
  for (int kt = 0; kt < 6; ++kt)
    areg[kt] = *(const bf16x8*)&bufA[(mt << 4) + lr][lg * 8 + kt * 32];
  #pragma unroll
  for (int t = 0; t < 6; ++t) acc[t] = (f32x4){0.f, 0.f, 0.f, 0.f};
  #pragma unroll
  for (int kt = 0; kt < 6; ++kt) {
    #pragma unroll
    for (int t = 0; t < 6; ++t) {
      int n = (wn + 2 * t) * 16 + lr;
      bf16x8 b = *(const bf16x8*)(Wb1 + (size_t)n * KK + lg * 8 + kt * 32);
      acc[t] = __builtin_amdgcn_mfma_f32_16x16x32_bf16(areg[kt], b, acc[t], 0, 0, 0);
    }
  }
  #pragma unroll
  for (int t = 0; t < 6; ++t) {
    int n = (wn + 2 * t) * 16 + lr;
    float bias = b1[n];
    int rowb = (mt << 4) + (lg << 2);
    #pragma unroll
    for (int q = 0; q < 4; ++q)
      bufB[rowb + q][n] = f2bf(mish_f(acc[t][q] + bias));
  }
  __syncthreads();

  // ---- GEMM2: t2 = mish(t1 @ W2^T + b2) -> bufA ----
  #pragma unroll
  for (int kt = 0; kt < 6; ++kt)
    areg[kt] = *(const bf16x8*)&bufB[(mt << 4) + lr][lg * 8 + kt * 32];
  #pragma unroll
  for (int t = 0; t < 6; ++t) acc[t] = (f32x4){0.f, 0.f, 0.f, 0.f};
  #pragma unroll
  for (int kt = 0; kt < 6; ++kt) {
    #pragma unroll
    for (int t = 0; t < 6; ++t) {
      int n = (wn + 2 * t) * 16 + lr;
      bf16x8 b = *(const bf16x8*)(Wb2 + (size_t)n * KK + lg * 8 + kt * 32);
      acc[t] = __builtin_amdgcn_mfma_f32_16x16x32_bf16(areg[kt], b, acc[t], 0, 0, 0);
    }
  }
  __syncthreads();  // bufA reads (GEMM1) are 2 syncs back; safe to overwrite
  #pragma unroll
  for (int t = 0; t < 6; ++t) {
    int n = (wn + 2 * t) * 16 + lr;
    float bias = b2[n];
    int rowb = (mt << 4) + (lg << 2);
    #pragma unroll
    for (int q = 0; q < 4; ++q)
      bufA[rowb + q][n] = f2bf(mish_f(acc[t][q] + bias));
  }
  __syncthreads();

  // ---- GEMM3: t3 = t2 @ W3^T + b3 -> global + sumsq ----
  #pragma unroll
  for (int kt = 0; kt < 6; ++kt)
    areg[kt] = *(const bf16x8*)&bufA[(mt << 4) + lr][lg * 8 + kt * 32];
  f32x4 a3[2];
  a3[0] = (f32x4){0.f, 0.f, 0.f, 0.f};
  a3[1] = (f32x4){0.f, 0.f, 0.f, 0.f};
  #pragma unroll
  for (int kt = 0; kt < 6; ++kt) {
    #pragma unroll
    for (int t = 0; t < 2; ++t) {
      int n = (wn + 2 * t) * 16 + lr;
      bf16x8 b = *(const bf16x8*)(Wb3 + (size_t)n * KK + lg * 8 + kt * 32);
      a3[t] = __builtin_amdgcn_mfma_f32_16x16x32_bf16(areg[kt], b, a3[t], 0, 0, 0);
    }
  }
  float lss = 0.f;
  #pragma unroll
  for (int t = 0; t < 2; ++t) {
    int n = (wn + 2 * t) * 16 + lr;
    float bias = b3[n];
    int rowb = r0 + (mt << 4) + (lg << 2);
    #pragma unroll
    for (int q = 0; q < 4; ++q) {
      float v = a3[t][q] + bias;
      t3out[(((size_t)(rowb + q)) << 6) + n] = v;
      lss = fmaf(v, v, lss);
    }
  }
  #pragma unroll
  for (int off = 32; off > 0; off >>= 1) lss += __shfl_down(lss, off);
  if (l == 0) ssred[w] = lss;
  __syncthreads();
  if (tid == 0) atomicAdd(sumsq, ssred[0] + ssred[1] + ssred[2] + ssred[3]);
}

__global__ void finalize_kernel(const float* __restrict__ t3, const float* __restrict__ sumsq,
                                const float* __restrict__ aout, ushort* __restrict__ egoh,
                                float* __restrict__ outacc, int last) {
  size_t i = (size_t)blockIdx.x * blockDim.x + threadIdx.x;
  size_t total = (size_t)UIN * DN;
  if (i >= total) return;
  size_t usz = (size_t)UN * DN;
  float v;
  if (i < usz) {
    float inv = 1.0f / sqrtf(sumsq[0]);
    v = t3[i] * inv;
  } else {
    v = aout[i];
  }
  if (last) {
    outacc[i] = (outacc[i] + v) * 0.25f;
  } else {
    egoh[i] = f2bf(v);
    outacc[i] += v;
  }
}

extern "C" void kernel_launch(void* const* d_in, const int* in_sizes, int n_in,
                              void* d_out, int out_size, void* d_ws, size_t ws_size,
                              hipStream_t stream) {
  const float* user_emb = (const float*)d_in[0];
  const float* item_emb = (const float*)d_in[1];
  const int* A_rows = (const int*)d_in[2];
  const int* A_cols = (const int*)d_in[3];
  const float* A_vals = (const float*)d_in[4];
  const int* S_rows = (const int*)d_in[5];
  const int* S_cols = (const int*)d_in[6];
  const float* S_vals = (const float*)d_in[7];
  const float* W1 = (const float*)d_in[8];
  const float* b1 = (const float*)d_in[9];
  const float* W2 = (const float*)d_in[10];
  const float* b2 = (const float*)d_in[11];
  const float* W3 = (const float*)d_in[12];
  const float* b3 = (const float*)d_in[13];
  const int nnzA = in_sizes[2];
  const int nnzS = in_sizes[5];

  float* ws = (float*)d_ws;
  size_t off = 0;
  ushort* egoh = (ushort*)(ws + off); off += (size_t)UIN * DN / 2;  // bf16 embeddings
  float* aout = ws + off; off += (size_t)UIN * DN;
  float* sout = ws + off; off += (size_t)UN * DN;   // aliased as t3 (per-block read-then-write)
  float* ss = ws + off;   off += 16;
  ushort* Wb1 = (ushort*)(ws + off); off += KK * KK / 2;
  ushort* Wb2 = (ushort*)(ws + off); off += KK * KK / 2;
  ushort* Wb3 = (ushort*)(ws + off); off += KK * DN / 2;
  int* cnt = (int*)(ws + off);    off += NROWS_ALL;        // A rows then S rows
  int* rowptr = (int*)(ws + off); off += NROWS_ALL + 1;    // combined
  int* tmp = (int*)(ws + off);    off += NROWS_ALL;
  int* bsum = (int*)(ws + off);   off += 1024;
  off = (off + 1) & ~(size_t)1;  // 8B align
  const size_t padAll = (size_t)nnzA + (size_t)nnzS + 4 * NROWS_ALL;
  int2* pAll = (int2*)(ws + off); off += 2 * padAll;
  float* outacc = (float*)d_out;
  float* t3 = sout;

  const size_t total = (size_t)UIN * DN;
  const int nblk_elem = (int)((total + 255) / 256);
  const int nbScan = (NROWS_ALL + 255) / 256;  // 977 <= 1024

  // CSR build (combined): hist -> hierarchical padded scan -> scatter
  hipMemsetAsync(cnt, 0, (size_t)NROWS_ALL * sizeof(int), stream);
  hipMemsetAsync(pAll, 0, padAll * sizeof(int2), stream);
  hist_kernel<<<(nnzA + 255) / 256, 256, 0, stream>>>(A_rows, cnt, nnzA);
  hist_kernel<<<(nnzS + 255) / 256, 256, 0, stream>>>(S_rows, cnt + UIN, nnzS);
  scan1<<<nbScan, 256, 0, stream>>>(cnt, rowptr, bsum, NROWS_ALL);
  scan2<<<1, 1024, 0, stream>>>(bsum, nbScan);
  scan3<<<nbScan, 256, 0, stream>>>(rowptr, bsum, cnt, tmp, NROWS_ALL);
  scatter_kernel<<<(nnzA + 255) / 256, 256, 0, stream>>>(A_rows, A_cols, A_vals, tmp, pAll, nnzA);
  scatter_kernel<<<(nnzS + 255) / 256, 256, 0, stream>>>(S_rows, S_cols, S_vals, tmp + UIN, pAll, nnzS);

  init_kernel<<<nblk_elem, 256, 0, stream>>>(user_emb, item_emb, egoh, outacc);
  convert_w<<<(KK * KK + 255) / 256, 256, 0, stream>>>(W1, Wb1, KK * KK);
  convert_w<<<(KK * KK + 255) / 256, 256, 0, stream>>>(W2, Wb2, KK * KK);
  convert_w<<<(KK * DN + 255) / 256, 256, 0, stream>>>(W3, Wb3, KK * DN);

  for (int layer = 0; layer < 3; ++layer) {
    hipMemsetAsync(ss, 0, 64, stream);
    spmm4<<<(UIN + 3) / 4, 256, 0, stream>>>(rowptr, pAll, egoh, aout, UIN);
    spmm4<<<(UN + 3) / 4, 256, 0, stream>>>(rowptr + UIN, pAll, egoh, sout, UN);
    fusion_mfma<<<UN / TILE, 256, 0, stream>>>(aout, sout, Wb1, b1, Wb2, b2, Wb3, b3, t3, ss);
    finalize_kernel<<<nblk_elem, 256, 0, stream>>>(t3, ss, aout, egoh, outacc, layer == 2);
  }
}

// Round 13
// 1314.499 us; speedup vs baseline: 2.5837x; 1.1393x over previous
//
#include <hip/hip_runtime.h>

#define UN 100000
#define INN 50000
#define UIN 150000
#define DN 64
#define KK 192
#define TILE 32
#define LPAD 200  // ushort cols per LDS row: 400B stride, 16B-aligned, <=2-way banks
#define NROWS_ALL (UIN + UN)

typedef __attribute__((ext_vector_type(8))) short bf16x8;
typedef __attribute__((ext_vector_type(4))) float f32x4;

// mish(x) = x * (t^2 + 2t) / (t^2 + 2t + 2), t = e^x
__device__ __forceinline__ float mish_f(float x) {
  float t = __expf(x);
  float num = fmaf(t, t, 2.0f * t);
  float m = x * num / (num + 2.0f);
  return (x > 20.0f) ? x : m;
}

__device__ __forceinline__ float bf2f(ushort u) {
  return __uint_as_float(((unsigned int)u) << 16);
}
__device__ __forceinline__ ushort f2bf(float f) {  // RNE
  unsigned int u = __float_as_uint(f);
  u += 0x7FFFu + ((u >> 16) & 1u);
  return (ushort)(u >> 16);
}

__global__ void init_kernel(const float* __restrict__ ue, const float* __restrict__ ie,
                            ushort* __restrict__ egoh, float* __restrict__ outacc) {
  size_t i = (size_t)blockIdx.x * blockDim.x + threadIdx.x;
  size_t total = (size_t)UIN * DN;
  if (i >= total) return;
  size_t usz = (size_t)UN * DN;
  float v = (i < usz) ? ue[i] : ie[i - usz];
  egoh[i] = f2bf(v);
  outacc[i] = v;
}

__global__ void convert_w(const float* __restrict__ W, ushort* __restrict__ Wb, int n) {
  int i = blockIdx.x * blockDim.x + threadIdx.x;
  if (i < n) Wb[i] = f2bf(W[i]);
}

// ---------------- CSR build: combined A(+0) and S(+UIN) rows, lists padded to x4 ----------------
__global__ void hist_kernel(const int* __restrict__ rows, int* __restrict__ cnt, int nnz) {
  int e = blockIdx.x * blockDim.x + threadIdx.x;
  if (e < nnz) atomicAdd(&cnt[rows[e]], 1);
}

// level 0: per-block (256) inclusive scan of padded counts -> exclusive offsets + block sums
__global__ __launch_bounds__(256) void scan1(const int* __restrict__ cnt,
                                             int* __restrict__ rowptr,
                                             int* __restrict__ bsum, int n) {
  __shared__ int sh[256];
  int i = blockIdx.x * 256 + threadIdx.x;
  int v = (i < n) ? ((cnt[i] + 3) & ~3) : 0;
  sh[threadIdx.x] = v;
  __syncthreads();
  #pragma unroll
  for (int off = 1; off < 256; off <<= 1) {
    int t = (threadIdx.x >= off) ? sh[threadIdx.x - off] : 0;
    __syncthreads();
    sh[threadIdx.x] += t;
    __syncthreads();
  }
  if (i < n) rowptr[i] = sh[threadIdx.x] - v;
  if (threadIdx.x == 255) bsum[blockIdx.x] = sh[255];
}

// level 1: single-block scan of block sums (nb <= 1024)
__global__ __launch_bounds__(1024) void scan2(int* __restrict__ bsum, int nb) {
  __shared__ int sh[1024];
  int tid = threadIdx.x;
  int v = (tid < nb) ? bsum[tid] : 0;
  sh[tid] = v;
  __syncthreads();
  #pragma unroll
  for (int off = 1; off < 1024; off <<= 1) {
    int t = (tid >= off) ? sh[tid - off] : 0;
    __syncthreads();
    sh[tid] += t;
    __syncthreads();
  }
  if (tid < nb) bsum[tid] = sh[tid] - v;  // exclusive
}

// level 2: add block offsets; produce rowptr + scatter cursors + final total
__global__ void scan3(int* __restrict__ rowptr, const int* __restrict__ bsum,
                      const int* __restrict__ cnt, int* __restrict__ tmp, int n) {
  int i = blockIdx.x * 256 + threadIdx.x;
  if (i >= n) return;
  int r = rowptr[i] + bsum[i >> 8];
  rowptr[i] = r;
  tmp[i] = r;
  if (i == n - 1) rowptr[n] = r + ((cnt[i] + 3) & ~3);
}

__global__ void scatter_kernel(const int* __restrict__ rows, const int* __restrict__ cols,
                               const float* __restrict__ vals, int* __restrict__ tmp,
                               int2* __restrict__ packed, int nnz) {
  int e = blockIdx.x * blockDim.x + threadIdx.x;
  if (e >= nnz) return;
  int pos = atomicAdd(&tmp[rows[e]], 1);
  packed[pos] = make_int2(cols[e], __float_as_int(vals[e]));
}

// ---------------- SpMM: wave = 1 row, 16 lanes/row-slice, 4 edge slots, 4-deep ILP ----------------
__global__ __launch_bounds__(256) void spmm4(const int* __restrict__ rowptr,
                                             const int2* __restrict__ packed,
                                             const ushort* __restrict__ xh,
                                             float* __restrict__ out, int nrows) {
  int r = blockIdx.x * 4 + (threadIdx.x >> 6);
  if (r >= nrows) return;
  int l = threadIdx.x & 63;
  int sub = l >> 4;        // edge slot 0..3
  int c16 = l & 15;        // feature group (4 bf16)
  int beg = rowptr[r], end = rowptr[r + 1];  // count multiple of 4 (padded, val=0)
  float4 A0 = make_float4(0.f, 0.f, 0.f, 0.f);
  float4 A1 = make_float4(0.f, 0.f, 0.f, 0.f);
  float4 A2 = make_float4(0.f, 0.f, 0.f, 0.f);
  float4 A3 = make_float4(0.f, 0.f, 0.f, 0.f);
  int e = beg + sub;
  for (; e + 12 < end; e += 16) {
    int2 p0 = packed[e];
    int2 p1 = packed[e + 4];
    int2 p2 = packed[e + 8];
    int2 p3 = packed[e + 12];
    ushort4 x0 = *(const ushort4*)(xh + (((size_t)p0.x) << 6) + (c16 << 2));
    ushort4 x1 = *(const ushort4*)(xh + (((size_t)p1.x) << 6) + (c16 << 2));
    ushort4 x2 = *(const ushort4*)(xh + (((size_t)p2.x) << 6) + (c16 << 2));
    ushort4 x3 = *(const ushort4*)(xh + (((size_t)p3.x) << 6) + (c16 << 2));
    float v0 = __int_as_float(p0.y);
    float v1 = __int_as_float(p1.y);
    float v2 = __int_as_float(p2.y);
    float v3 = __int_as_float(p3.y);
    A0.x = fmaf(v0, bf2f(x0.x), A0.x); A0.y = fmaf(v0, bf2f(x0.y), A0.y);
    A0.z = fmaf(v0, bf2f(x0.z), A0.z); A0.w = fmaf(v0, bf2f(x0.w), A0.w);
    A1.x = fmaf(v1, bf2f(x1.x), A1.x); A1.y = fmaf(v1, bf2f(x1.y), A1.y);
    A1.z = fmaf(v1, bf2f(x1.z), A1.z); A1.w = fmaf(v1, bf2f(x1.w), A1.w);
    A2.x = fmaf(v2, bf2f(x2.x), A2.x); A2.y = fmaf(v2, bf2f(x2.y), A2.y);
    A2.z = fmaf(v2, bf2f(x2.z), A2.z); A2.w = fmaf(v2, bf2f(x2.w), A2.w);
    A3.x = fmaf(v3, bf2f(x3.x), A3.x); A3.y = fmaf(v3, bf2f(x3.y), A3.y);
    A3.z = fmaf(v3, bf2f(x3.z), A3.z); A3.w = fmaf(v3, bf2f(x3.w), A3.w);
  }
  for (; e < end; e += 4) {
    int2 p = packed[e];
    ushort4 xv = *(const ushort4*)(xh + (((size_t)p.x) << 6) + (c16 << 2));
    float v = __int_as_float(p.y);
    A0.x = fmaf(v, bf2f(xv.x), A0.x); A0.y = fmaf(v, bf2f(xv.y), A0.y);
    A0.z = fmaf(v, bf2f(xv.z), A0.z); A0.w = fmaf(v, bf2f(xv.w), A0.w);
  }
  A0.x += A1.x + A2.x + A3.x;
  A0.y += A1.y + A2.y + A3.y;
  A0.z += A1.z + A2.z + A3.z;
  A0.w += A1.w + A2.w + A3.w;
  A0.x += __shfl_xor(A0.x, 16); A0.y += __shfl_xor(A0.y, 16);
  A0.z += __shfl_xor(A0.z, 16); A0.w += __shfl_xor(A0.w, 16);
  A0.x += __shfl_xor(A0.x, 32); A0.y += __shfl_xor(A0.y, 32);
  A0.z += __shfl_xor(A0.z, 32); A0.w += __shfl_xor(A0.w, 32);
  if (sub == 0) *(float4*)(out + (((size_t)r) << 6) + (c16 << 2)) = A0;
}

// ---------------- Fused 3-GEMM MLP via MFMA, 256 threads, 32-row tile ----------------
// Wave w owns BOTH 16-row halves and a 48-col N-quarter -> 2 MFMA per weight load.
// mfma_f32_16x16x32_bf16: A lane l: row=l&15, k=(l>>4)*8+r ; B lane l: col=l&15, k=(l>>4)*8+r
// D lane l: col=l&15, row=(l>>4)*4+reg  [m89/m91 verified]
__global__ __launch_bounds__(256, 4) void fusion_mfma(
    const float* __restrict__ aout, const float* __restrict__ sout,
    const ushort* __restrict__ Wb1, const float* __restrict__ b1,
    const ushort* __restrict__ Wb2, const float* __restrict__ b2,
    const ushort* __restrict__ Wb3, const float* __restrict__ b3,
    float* __restrict__ t3out, float* __restrict__ sumsq) {
  __shared__ ushort bufA[TILE][LPAD];  // cat, later t2
  __shared__ ushort bufB[TILE][LPAD];  // t1
  __shared__ float ssred[4];
  const int tid = threadIdx.x;
  const int w = tid >> 6;      // wave 0..3 = N-quarter
  const int l = tid & 63;
  const int lg = l >> 4;       // lane group 0..3
  const int lr = l & 15;
  const int r0 = blockIdx.x * TILE;  // UN = 3125*32

  // ---- stage cat = [u, s, u*s] as bf16, row-major [32][192] ----
  {
    int row = tid >> 3;
    int c0 = (tid & 7) * 8;
    const float4* ap = (const float4*)(aout + (((size_t)(r0 + row)) << 6) + c0);
    const float4* sp = (const float4*)(sout + (((size_t)(r0 + row)) << 6) + c0);
    float4 u0 = ap[0], u1 = ap[1];
    float4 s0 = sp[0], s1 = sp[1];
    float uu[8] = {u0.x, u0.y, u0.z, u0.w, u1.x, u1.y, u1.z, u1.w};
    float ssv[8] = {s0.x, s0.y, s0.z, s0.w, s1.x, s1.y, s1.z, s1.w};
    bf16x8 vu, vs, vm;
    #pragma unroll
    for (int j = 0; j < 8; ++j) {
      vu[j] = (short)f2bf(uu[j]);
      vs[j] = (short)f2bf(ssv[j]);
      vm[j] = (short)f2bf(uu[j] * ssv[j]);
    }
    *(bf16x8*)&bufA[row][c0] = vu;
    *(bf16x8*)&bufA[row][64 + c0] = vs;
    *(bf16x8*)&bufA[row][128 + c0] = vm;
  }
  __syncthreads();

  bf16x8 areg[2][6];
  f32x4 acc[2][3];

  // ---- GEMM1: t1 = mish(cat @ W1^T + b1) -> bufB ----
  #pragma unroll
  for (int mt = 0; mt < 2; ++mt)
    #pragma unroll
    for (int kt = 0; kt < 6; ++kt)
      areg[mt][kt] = *(const bf16x8*)&bufA[(mt << 4) + lr][lg * 8 + kt * 32];
  #pragma unroll
  for (int mt = 0; mt < 2; ++mt)
    #pragma unroll
    for (int t = 0; t < 3; ++t) acc[mt][t] = (f32x4){0.f, 0.f, 0.f, 0.f};
  #pragma unroll
  for (int kt = 0; kt < 6; ++kt) {
    #pragma unroll
    for (int t = 0; t < 3; ++t) {
      int n = (3 * w + t) * 16 + lr;
      bf16x8 b = *(const bf16x8*)(Wb1 + (size_t)n * KK + lg * 8 + kt * 32);
      acc[0][t] = __builtin_amdgcn_mfma_f32_16x16x32_bf16(areg[0][kt], b, acc[0][t], 0, 0, 0);
      acc[1][t] = __builtin_amdgcn_mfma_f32_16x16x32_bf16(areg[1][kt], b, acc[1][t], 0, 0, 0);
    }
  }
  #pragma unroll
  for (int t = 0; t < 3; ++t) {
    int n = (3 * w + t) * 16 + lr;
    float bias = b1[n];
    #pragma unroll
    for (int mt = 0; mt < 2; ++mt) {
      int rowb = (mt << 4) + (lg << 2);
      #pragma unroll
      for (int q = 0; q < 4; ++q)
        bufB[rowb + q][n] = f2bf(mish_f(acc[mt][t][q] + bias));
    }
  }
  __syncthreads();

  // ---- GEMM2: t2 = mish(t1 @ W2^T + b2) -> bufA (bufA dead since pre-GEMM1 areg loads) ----
  #pragma unroll
  for (int mt = 0; mt < 2; ++mt)
    #pragma unroll
    for (int kt = 0; kt < 6; ++kt)
      areg[mt][kt] = *(const bf16x8*)&bufB[(mt << 4) + lr][lg * 8 + kt * 32];
  #pragma unroll
  for (int mt = 0; mt < 2; ++mt)
    #pragma unroll
    for (int t = 0; t < 3; ++t) acc[mt][t] = (f32x4){0.f, 0.f, 0.f, 0.f};
  #pragma unroll
  for (int kt = 0; kt < 6; ++kt) {
    #pragma unroll
    for (int t = 0; t < 3; ++t) {
      int n = (3 * w + t) * 16 + lr;
      bf16x8 b = *(const bf16x8*)(Wb2 + (size_t)n * KK + lg * 8 + kt * 32);
      acc[0][t] = __builtin_amdgcn_mfma_f32_16x16x32_bf16(areg[0][kt], b, acc[0][t], 0, 0, 0);
      acc[1][t] = __builtin_amdgcn_mfma_f32_16x16x32_bf16(areg[1][kt], b, acc[1][t], 0, 0, 0);
    }
  }
  #pragma unroll
  for (int t = 0; t < 3; ++t) {
    int n = (3 * w + t) * 16 + lr;
    float bias = b2[n];
    #pragma unroll
    for (int mt = 0; mt < 2; ++mt) {
      int rowb = (mt << 4) + (lg << 2);
      #pragma unroll
      for (int q = 0; q < 4; ++q)
        bufA[rowb + q][n] = f2bf(mish_f(acc[mt][t][q] + bias));
    }
  }
  __syncthreads();

  // ---- GEMM3: t3 = t2 @ W3^T + b3 -> global + sumsq; wave w = 16-col tile w ----
  #pragma unroll
  for (int mt = 0; mt < 2; ++mt)
    #pragma unroll
    for (int kt = 0; kt < 6; ++kt)
      areg[mt][kt] = *(const bf16x8*)&bufA[(mt << 4) + lr][lg * 8 + kt * 32];
  f32x4 a3[2];
  a3[0] = (f32x4){0.f, 0.f, 0.f, 0.f};
  a3[1] = (f32x4){0.f, 0.f, 0.f, 0.f};
  const int n3 = w * 16 + lr;
  #pragma unroll
  for (int kt = 0; kt < 6; ++kt) {
    bf16x8 b = *(const bf16x8*)(Wb3 + (size_t)n3 * KK + lg * 8 + kt * 32);
    a3[0] = __builtin_amdgcn_mfma_f32_16x16x32_bf16(areg[0][kt], b, a3[0], 0, 0, 0);
    a3[1] = __builtin_amdgcn_mfma_f32_16x16x32_bf16(areg[1][kt], b, a3[1], 0, 0, 0);
  }
  float b3v = b3[n3];
  float lss = 0.f;
  #pragma unroll
  for (int mt = 0; mt < 2; ++mt) {
    int rowb = r0 + (mt << 4) + (lg << 2);
    #pragma unroll
    for (int q = 0; q < 4; ++q) {
      float v = a3[mt][q] + b3v;
      t3out[(((size_t)(rowb + q)) << 6) + n3] = v;
      lss = fmaf(v, v, lss);
    }
  }
  #pragma unroll
  for (int off = 32; off > 0; off >>= 1) lss += __shfl_down(lss, off);
  if (l == 0) ssred[w] = lss;
  __syncthreads();
  if (tid == 0) atomicAdd(sumsq, ssred[0] + ssred[1] + ssred[2] + ssred[3]);
}

__global__ void finalize_kernel(const float* __restrict__ t3, const float* __restrict__ sumsq,
                                const float* __restrict__ aout, ushort* __restrict__ egoh,
                                float* __restrict__ outacc, int last) {
  size_t i = (size_t)blockIdx.x * blockDim.x + threadIdx.x;
  size_t total = (size_t)UIN * DN;
  if (i >= total) return;
  size_t usz = (size_t)UN * DN;
  float v;
  if (i < usz) {
    float inv = 1.0f / sqrtf(sumsq[0]);
    v = t3[i] * inv;
  } else {
    v = aout[i];
  }
  if (last) {
    outacc[i] = (outacc[i] + v) * 0.25f;
  } else {
    egoh[i] = f2bf(v);
    outacc[i] += v;
  }
}

extern "C" void kernel_launch(void* const* d_in, const int* in_sizes, int n_in,
                              void* d_out, int out_size, void* d_ws, size_t ws_size,
                              hipStream_t stream) {
  const float* user_emb = (const float*)d_in[0];
  const float* item_emb = (const float*)d_in[1];
  const int* A_rows = (const int*)d_in[2];
  const int* A_cols = (const int*)d_in[3];
  const float* A_vals = (const float*)d_in[4];
  const int* S_rows = (const int*)d_in[5];
  const int* S_cols = (const int*)d_in[6];
  const float* S_vals = (const float*)d_in[7];
  const float* W1 = (const float*)d_in[8];
  const float* b1 = (const float*)d_in[9];
  const float* W2 = (const float*)d_in[10];
  const float* b2 = (const float*)d_in[11];
  const float* W3 = (const float*)d_in[12];
  const float* b3 = (const float*)d_in[13];
  const int nnzA = in_sizes[2];
  const int nnzS = in_sizes[5];

  float* ws = (float*)d_ws;
  size_t off = 0;
  ushort* egoh = (ushort*)(ws + off); off += (size_t)UIN * DN / 2;  // bf16 embeddings
  float* aout = ws + off; off += (size_t)UIN * DN;
  float* sout = ws + off; off += (size_t)UN * DN;   // aliased as t3 (per-block read-then-write)
  float* ss = ws + off;   off += 16;
  ushort* Wb1 = (ushort*)(ws + off); off += KK * KK / 2;
  ushort* Wb2 = (ushort*)(ws + off); off += KK * KK / 2;
  ushort* Wb3 = (ushort*)(ws + off); off += KK * DN / 2;
  int* cnt = (int*)(ws + off);    off += NROWS_ALL;        // A rows then S rows
  int* rowptr = (int*)(ws + off); off += NROWS_ALL + 1;    // combined
  int* tmp = (int*)(ws + off);    off += NROWS_ALL;
  int* bsum = (int*)(ws + off);   off += 1024;
  off = (off + 1) & ~(size_t)1;  // 8B align
  const size_t padAll = (size_t)nnzA + (size_t)nnzS + 4 * NROWS_ALL;
  int2* pAll = (int2*)(ws + off); off += 2 * padAll;
  float* outacc = (float*)d_out;
  float* t3 = sout;

  const size_t total = (size_t)UIN * DN;
  const int nblk_elem = (int)((total + 255) / 256);
  const int nbScan = (NROWS_ALL + 255) / 256;  // 977 <= 1024

  // CSR build (combined): hist -> hierarchical padded scan -> scatter
  hipMemsetAsync(cnt, 0, (size_t)NROWS_ALL * sizeof(int), stream);
  hipMemsetAsync(pAll, 0, padAll * sizeof(int2), stream);
  hist_kernel<<<(nnzA + 255) / 256, 256, 0, stream>>>(A_rows, cnt, nnzA);
  hist_kernel<<<(nnzS + 255) / 256, 256, 0, stream>>>(S_rows, cnt + UIN, nnzS);
  scan1<<<nbScan, 256, 0, stream>>>(cnt, rowptr, bsum, NROWS_ALL);
  scan2<<<1, 1024, 0, stream>>>(bsum, nbScan);
  scan3<<<nbScan, 256, 0, stream>>>(rowptr, bsum, cnt, tmp, NROWS_ALL);
  scatter_kernel<<<(nnzA + 255) / 256, 256, 0, stream>>>(A_rows, A_cols, A_vals, tmp, pAll, nnzA);
  scatter_kernel<<<(nnzS + 255) / 256, 256, 0, stream>>>(S_rows, S_cols, S_vals, tmp + UIN, pAll, nnzS);

  init_kernel<<<nblk_elem, 256, 0, stream>>>(user_emb, item_emb, egoh, outacc);
  convert_w<<<(KK * KK + 255) / 256, 256, 0, stream>>>(W1, Wb1, KK * KK);
  convert_w<<<(KK * KK + 255) / 256, 256, 0, stream>>>(W2, Wb2, KK * KK);
  convert_w<<<(KK * DN + 255) / 256, 256, 0, stream>>>(W3, Wb3, KK * DN);

  for (int layer = 0; layer < 3; ++layer) {
    hipMemsetAsync(ss, 0, 64, stream);
    spmm4<<<(UIN + 3) / 4, 256, 0, stream>>>(rowptr, pAll, egoh, aout, UIN);
    spmm4<<<(UN + 3) / 4, 256, 0, stream>>>(rowptr + UIN, pAll, egoh, sout, UN);
    fusion_mfma<<<UN / TILE, 256, 0, stream>>>(aout, sout, Wb1, b1, Wb2, b2, Wb3, b3, t3, ss);
    finalize_kernel<<<nblk_elem, 256, 0, stream>>>(t3, ss, aout, egoh, outacc, layer == 2);
  }
}